// Round 4
// baseline (471.530 us; speedup 1.0000x reference)
//
#include <hip/hip_runtime.h>
#include <hip/hip_bf16.h>

#define NODES   100000
#define EDGES   1600000
#define INDIM   128
#define HID     64
#define NCLS    40
#define NEG_BIG_F (-9000000000000000.0f)
#define SENTINEL  (-3.0e38f)

#define BN       512                 // dst-nodes per coarse bucket (dst >> 9)
#define NBUCK    196                 // ceil(100000/512)
#define CHUNK    7168                // edges per phase-A block
#define NCHUNK   ((EDGES + CHUNK - 1) / CHUNK)   // 224
#define BCAP     8960                // phase-B stage capacity (mean 8192)
#define MZPB     256                 // node-mz partial blocks

static __device__ __forceinline__ float b2f(__hip_bfloat16 h){
    return __bfloat162float(h);
}
static __device__ __forceinline__ float bits2f(unsigned int b){
    union { unsigned int u; float f; } v; v.u = b << 16; return v.f;
}
static __device__ __forceinline__ unsigned short f2b(float f){
    __hip_bfloat16 h = __float2bfloat16(f);
    return *reinterpret_cast<unsigned short*>(&h);
}
static __device__ __forceinline__ float ldin(const void* p, int i, bool f32){
    return f32 ? ((const float*)p)[i] : b2f(((const __hip_bfloat16*)p)[i]);
}
// fast ELU: expm1f is a ~30-instruction libm expansion; __expf(x)-1 is 3 instr,
// abs error ~1e-7 -- irrelevant vs the 7.4e-2 test threshold.
static __device__ __forceinline__ float elu_fast(float x){
    return (x > 0.f) ? x : (__expf(x) - 1.f);
}
// order-preserving float<->uint encoding for atomicMax on floats
static __device__ __forceinline__ unsigned fenc(float f){
    unsigned u = __float_as_uint(f);
    return (u & 0x80000000u) ? ~u : (u | 0x80000000u);
}
static __device__ __forceinline__ float fdec(unsigned k){
    return __uint_as_float((k & 0x80000000u) ? (k & 0x7fffffffu) : ~k);
}
static __device__ __forceinline__ void unpack8(uint4 u, float* o){
    o[0]=bits2f(u.x & 0xffffu); o[1]=bits2f(u.x >> 16);
    o[2]=bits2f(u.y & 0xffffu); o[3]=bits2f(u.y >> 16);
    o[4]=bits2f(u.z & 0xffffu); o[5]=bits2f(u.z >> 16);
    o[6]=bits2f(u.w & 0xffffu); o[7]=bits2f(u.w >> 16);
}
static __device__ __forceinline__ int ld_src(const int* ei, int i, bool i64){
    return i64 ? ei[2*i] : ei[i];
}
static __device__ __forceinline__ int ld_dst(const int* ei, int i, bool i64){
    return i64 ? ei[2*(EDGES + i)] : ei[EDGES + i];
}

// flags[0]=1 if floats are fp32; flags[1]=1 if edge_index is int64
__global__ __launch_bounds__(256) void k_detect(const unsigned* __restrict__ xw,
                                                const unsigned* __restrict__ eiw,
                                                int* __restrict__ flags){
    __shared__ int s1[256], s2[256];
    int t = threadIdx.x;
    int c1 = 0, c2 = 0;
    for(int i = t; i < 1024; i += 256){
        unsigned e = (xw[i] >> 23) & 0xffu;
        c1 += (e >= 90u && e <= 160u) ? 1 : 0;
        c2 += (eiw[2*i + 1] == 0u) ? 1 : 0;
    }
    s1[t] = c1; s2[t] = c2; __syncthreads();
    for(int off = 128; off > 0; off >>= 1){
        if(t < off){ s1[t] += s1[t+off]; s2[t] += s2[t+off]; }
        __syncthreads();
    }
    if(t == 0){ flags[0] = (s1[0] > 512) ? 1 : 0; flags[1] = (s2[0] > 512) ? 1 : 0; }
}

// ---------------- bucket histogram ----------------
__global__ __launch_bounds__(256) void k_bhist(const int* __restrict__ ei,
                                               const int* __restrict__ flags,
                                               int* __restrict__ bdeg){
    __shared__ int sh[NBUCK];
    bool i64 = flags[1] != 0;
    int t = threadIdx.x;
    for(int i = t; i < NBUCK; i += 256) sh[i] = 0;
    __syncthreads();
    int i = blockIdx.x*256 + t;
    int stride = gridDim.x*256;
    for(; i < EDGES; i += stride) atomicAdd(&sh[ld_dst(ei, i, i64) >> 9], 1);
    __syncthreads();
    for(int b = t; b < NBUCK; b += 256) if(sh[b]) atomicAdd(&bdeg[b], sh[b]);
}

// parallel exclusive scan over NBUCK buckets
__global__ __launch_bounds__(256) void k_bscan(const int* __restrict__ bdeg,
                        int* __restrict__ bstart, int* __restrict__ bcursor){
    __shared__ int sh[256];
    int t = threadIdx.x;
    int v = (t < NBUCK) ? bdeg[t] : 0;
    sh[t] = v; __syncthreads();
    for(int off = 1; off < 256; off <<= 1){
        int x = (t >= off) ? sh[t - off] : 0;
        __syncthreads();
        sh[t] += x;
        __syncthreads();
    }
    int excl = sh[t] - v;
    if(t < NBUCK){ bstart[t] = excl; bcursor[t] = excl; }
    if(t == 255) bstart[NBUCK] = sh[255];
}

// ---------------- phase A: LDS-binned coarse scatter ----------------
__global__ __launch_bounds__(256) void k_bucket_scatter(const int* __restrict__ ei,
    const int* __restrict__ flags, int* __restrict__ bcursor, int2* __restrict__ tmp){
    __shared__ int  sCnt[NBUCK], sScan[NBUCK], sCur[NBUCK], sGofs[NBUCK];
    __shared__ int2 stage[CHUNK];
    bool i64 = flags[1] != 0;
    int t = threadIdx.x;
    int base = blockIdx.x * CHUNK;
    int n = EDGES - base; if(n > CHUNK) n = CHUNK; if(n <= 0) return;

    for(int b = t; b < NBUCK; b += 256) sCnt[b] = 0;
    __syncthreads();
    for(int j = t; j < n; j += 256)
        atomicAdd(&sCnt[ld_dst(ei, base + j, i64) >> 9], 1);
    __syncthreads();
    for(int b = t; b < NBUCK; b += 256) sScan[b] = sCnt[b];
    __syncthreads();
    for(int off = 1; off < NBUCK; off <<= 1){
        int v = 0;
        if(t < NBUCK && t >= off) v = sScan[t - off];
        __syncthreads();
        if(t < NBUCK) sScan[t] += v;
        __syncthreads();
    }
    if(t < NBUCK){
        int excl = sScan[t] - sCnt[t];
        sCur[t]  = excl;
        sGofs[t] = sCnt[t] ? atomicAdd(&bcursor[t], sCnt[t]) : 0;
    }
    __syncthreads();
    for(int j = t; j < n; j += 256){
        int src = ld_src(ei, base + j, i64);
        int dst = ld_dst(ei, base + j, i64);
        int pos = atomicAdd(&sCur[dst >> 9], 1);
        stage[pos] = make_int2(src, dst);
    }
    __syncthreads();
    for(int i = t; i < n; i += 256){
        int2 e = stage[i];
        int  b = e.y >> 9;
        int  excl = sScan[b] - sCnt[b];
        tmp[(size_t)sGofs[b] + (i - excl)] = e;
    }
}

// ---------------- phase B: per-bucket counting sort -> col + rowst ----------------
__global__ __launch_bounds__(512) void k_bucket_sort(const int2* __restrict__ tmp,
    const int* __restrict__ bstart, int* __restrict__ col,
    int* __restrict__ rowst){
    __shared__ int  sCnt[BN], sScan[BN], sCur[BN];
    __shared__ int2 stage[BCAP];
    int b = blockIdx.x, t = threadIdx.x;
    int nb0 = b * BN;
    int gbase = bstart[b], gend = bstart[b+1];
    int cnt = gend - gbase;

    if(t < BN) sCnt[t] = 0;
    __syncthreads();
    for(int j = gbase + t; j < gend; j += 512)
        atomicAdd(&sCnt[tmp[j].y - nb0], 1);
    __syncthreads();
    if(t < BN) sScan[t] = sCnt[t];
    __syncthreads();
    for(int off = 1; off < BN; off <<= 1){
        int v = 0;
        if(t < BN && t >= off) v = sScan[t - off];
        __syncthreads();
        if(t < BN) sScan[t] += v;
        __syncthreads();
    }
    if(t < BN) sCur[t] = sScan[t] - sCnt[t];
    if(t < BN && (nb0 + t) < NODES) rowst[nb0 + t] = gbase + (sScan[t] - sCnt[t]);
    if(b == 0 && t == 0) rowst[NODES] = EDGES;
    __syncthreads();
    for(int j = gbase + t; j < gend; j += 512){
        int2 e = tmp[j];
        int pos = atomicAdd(&sCur[e.y - nb0], 1);
        if(pos < BCAP) stage[pos] = e;
        else col[gbase + pos] = e.x;
    }
    __syncthreads();
    int lim = (cnt < BCAP) ? cnt : BCAP;
    for(int i = t; i < lim; i += 512)
        col[gbase + i] = stage[i].x;
}

// ---------------- GEMM: C[N x 64] = A[N x K] * W[K x 64] (+bias) (+score epilogue)
// SCALEA=1: A rows are unnormalized aggregates U; apply h = elu(U * exp(m_n - M) * invZ)
// during the A-load. WITH_SCORES also folds a global max-of-ssrc (S*) via atomicMax
// on an order-preserving uint encoding -- one atomic per wave.
template<int K, int AMODE, bool WITH_BIAS, bool WITH_SCORES, bool CBF16, int SCALEA>
__global__ __launch_bounds__(256) void k_gemm(
    const void* __restrict__ Aptr,
    const void* __restrict__ Wb,   int woff,
    const void* __restrict__ biasb,
    const void* __restrict__ attnb, int aoff,
    const int*  __restrict__ flags,
    void* __restrict__ Cout,
    float* __restrict__ s_src,
    float* __restrict__ s_dst,
    const float2* __restrict__ mzv,
    const float2* __restrict__ MZg,
    unsigned* __restrict__ smaxk)
{
    __shared__ float At[64][68];
    __shared__ float Wf[64][64];
    const bool wf32 = flags[0] != 0;
    const bool af32 = (AMODE == 2) ? true : wf32;
    const int t = threadIdx.x;
    const int block_row = blockIdx.x * 64;
    const int r_load = t >> 2;
    const int q_load = t & 3;
    const int grow_load = block_row + r_load;

    const int c0 = (t & 15) * 4;
    const int r0 = (t >> 4) * 4;

    float sA = 1.f;
    if constexpr (SCALEA == 1){
        float2 gz = MZg[0];
        float2 nm = (grow_load < NODES) ? mzv[grow_load] : make_float2(SENTINEL, 0.f);
        sA = __expf(nm.x - gz.x) * gz.y;
    }

    float acc[4][4] = {{0.f,0.f,0.f,0.f},{0.f,0.f,0.f,0.f},{0.f,0.f,0.f,0.f},{0.f,0.f,0.f,0.f}};

    for(int kb = 0; kb < K; kb += 64){
        if(wf32){
            const float4* wv = (const float4*)Wb;
            for(int v = t; v < 1024; v += 256){
                float4 u = wv[(size_t)(woff + kb*64)/4 + v];
                int f = v*4; int k = f >> 6; int c = f & 63;
                Wf[k][c]=u.x; Wf[k][c+1]=u.y; Wf[k][c+2]=u.z; Wf[k][c+3]=u.w;
            }
        } else {
            const uint4* wv = (const uint4*)Wb;
            for(int v = t; v < 512; v += 256){
                uint4 u = wv[(size_t)(woff + kb*64)/8 + v];
                float o[8]; unpack8(u, o);
                int f = v*8; int k = f >> 6; int c = f & 63;
                #pragma unroll
                for(int j=0;j<8;j++) Wf[k][c+j] = o[j];
            }
        }
        if(af32){
            const float4* av = (const float4*)Aptr;
            #pragma unroll
            for(int i=0;i<4;i++){
                int vi = q_load + 4*i;
                int k0 = vi*4;
                float4 u = make_float4(0.f,0.f,0.f,0.f);
                if(grow_load < NODES) u = av[(size_t)grow_load*(K/4) + (kb>>2) + vi];
                if constexpr (SCALEA == 1){
                    u.x = elu_fast(u.x*sA); u.y = elu_fast(u.y*sA);
                    u.z = elu_fast(u.z*sA); u.w = elu_fast(u.w*sA);
                }
                At[k0+0][r_load]=u.x; At[k0+1][r_load]=u.y;
                At[k0+2][r_load]=u.z; At[k0+3][r_load]=u.w;
            }
        } else {
            const uint4* av = (const uint4*)Aptr;
            #pragma unroll
            for(int i=0;i<2;i++){
                int vi = q_load + 4*i;
                int k0 = vi*8;
                float o[8];
                if(grow_load < NODES){
                    uint4 u = av[(size_t)grow_load*(K/8) + (kb>>3) + vi];
                    unpack8(u, o);
                } else {
                    #pragma unroll
                    for(int j=0;j<8;j++) o[j]=0.f;
                }
                #pragma unroll
                for(int j=0;j<8;j++) At[k0+j][r_load] = o[j];
            }
        }
        __syncthreads();
        #pragma unroll 8
        for(int k=0;k<64;k++){
            float4 a = *(const float4*)&At[k][r0];
            float4 w = *(const float4*)&Wf[k][c0];
            float av4[4] = {a.x,a.y,a.z,a.w};
            float wv4[4] = {w.x,w.y,w.z,w.w};
            #pragma unroll
            for(int i=0;i<4;i++)
                #pragma unroll
                for(int j=0;j<4;j++)
                    acc[i][j] = fmaf(av4[i], wv4[j], acc[i][j]);
        }
        __syncthreads();
    }

    float bias[4] = {0.f,0.f,0.f,0.f};
    if constexpr (WITH_BIAS){
        #pragma unroll
        for(int j=0;j<4;j++) bias[j] = ldin(biasb, c0+j, wf32);
    }
    #pragma unroll
    for(int i=0;i<4;i++){
        int grow = block_row + r0 + i;
        if(grow < NODES){
            if constexpr (CBF16){
                ushort4 o;
                o.x = f2b(acc[i][0]+bias[0]); o.y = f2b(acc[i][1]+bias[1]);
                o.z = f2b(acc[i][2]+bias[2]); o.w = f2b(acc[i][3]+bias[3]);
                *(ushort4*)((unsigned short*)Cout + (size_t)grow*64 + c0) = o;
            } else {
                float4 o = make_float4(acc[i][0]+bias[0], acc[i][1]+bias[1],
                                       acc[i][2]+bias[2], acc[i][3]+bias[3]);
                *(float4*)((float*)Cout + (size_t)grow*64 + c0) = o;
            }
        }
    }
    if constexpr (WITH_SCORES){
        float as[4], ad[4];
        #pragma unroll
        for(int j=0;j<4;j++){
            as[j] = ldin(attnb, aoff + c0+j, wf32);
            ad[j] = ldin(attnb, aoff + 64+c0+j, wf32);
        }
        float pmax = SENTINEL;
        #pragma unroll
        for(int i=0;i<4;i++){
            float ps = 0.f, pd = 0.f;
            #pragma unroll
            for(int j=0;j<4;j++){ ps = fmaf(acc[i][j], as[j], ps); pd = fmaf(acc[i][j], ad[j], pd); }
            for(int off=1; off<16; off<<=1){
                ps += __shfl_xor(ps, off, 64);
                pd += __shfl_xor(pd, off, 64);
            }
            int grow = block_row + r0 + i;
            if(grow < NODES) pmax = fmaxf(pmax, ps);
            if((t & 15) == 0 && grow < NODES){ s_src[grow] = ps; s_dst[grow] = pd; }
        }
        // wave max of ssrc -> one atomic per wave (order-preserving uint encoding)
        pmax = fmaxf(pmax, __shfl_xor(pmax, 16, 64));
        pmax = fmaxf(pmax, __shfl_xor(pmax, 32, 64));
        if((t & 63) == 0) atomicMax(smaxk, fenc(pmax));
    }
}

// ---------------- fused aggregate: fixed wave-uniform shift m_n = S* + sdst[n]
// (S* = global max ssrc, from gemm epilogue). att = ssrc[col]+sdst[n] <= m_n always,
// so w = exp(att - m_n) needs NO online max / rescale -- inner loop identical to the
// known-good Round-2 structure. Emits unnormalized U_n and (m_n, z_n); global
// normalization exp(m_n - M)/Z applied by the next consumer. Masked edges (v<=0)
// get att = NEG_BIG -> w = 0 exactly (matches reference underflow behavior).
__global__ __launch_bounds__(256) void k_aggregate(const unsigned short* __restrict__ wh16,
    const int* __restrict__ row_start, const int* __restrict__ col,
    const float* __restrict__ ssrc, const float* __restrict__ sdst,
    const unsigned* __restrict__ smaxk,
    float* __restrict__ U, float2* __restrict__ mz)
{
    int gw = (blockIdx.x*256 + threadIdx.x) >> 6;
    int lane = threadIdx.x & 63;
    if(gw >= NODES) return;
    int beg = row_start[gw], end = row_start[gw+1];
    int g  = lane >> 3;           // edge-group 0..7
    int c8 = (lane & 7) * 8;      // feature slice base
    float sdn = sdst[gw];
    const float m = fdec(*smaxk) + sdn;   // wave-uniform upper bound of att
    float zl = 0.f;
    float acc[8] = {0.f,0.f,0.f,0.f,0.f,0.f,0.f,0.f};
    for(int base = beg; base < end; base += 64){
        int idx = base + lane;
        bool vld = idx < end;
        int   s_l = vld ? col[idx] : 0;
        float v   = ssrc[s_l] + sdn;                 // hot 400KB gather
        float att = (vld && v > 0.f) ? v : NEG_BIG_F;
        float w_l = __expf(att - m);                 // in (0,1]; exactly 0 for masked
        zl += w_l;
        int n = end - base; if(n > 64) n = 64;
        int jmax = (n + 7) >> 3;
        int j = 0;
        for(; j + 2 <= jmax; j += 2){
            int k0 = 8*j + g, k1 = k0 + 8;
            float a0 = __shfl(w_l, k0, 64); int s0 = __shfl(s_l, k0, 64);
            float a1 = __shfl(w_l, k1, 64); int s1 = __shfl(s_l, k1, 64);
            bool p0 = (a0 != 0.f), p1 = (a1 != 0.f);
            uint4 u0, u1;
            if(p0) u0 = *(const uint4*)&wh16[(size_t)s0*64 + c8];
            if(p1) u1 = *(const uint4*)&wh16[(size_t)s1*64 + c8];
            if(p0){
                acc[0] = fmaf(a0, bits2f(u0.x & 0xffffu), acc[0]);
                acc[1] = fmaf(a0, bits2f(u0.x >> 16),     acc[1]);
                acc[2] = fmaf(a0, bits2f(u0.y & 0xffffu), acc[2]);
                acc[3] = fmaf(a0, bits2f(u0.y >> 16),     acc[3]);
                acc[4] = fmaf(a0, bits2f(u0.z & 0xffffu), acc[4]);
                acc[5] = fmaf(a0, bits2f(u0.z >> 16),     acc[5]);
                acc[6] = fmaf(a0, bits2f(u0.w & 0xffffu), acc[6]);
                acc[7] = fmaf(a0, bits2f(u0.w >> 16),     acc[7]);
            }
            if(p1){
                acc[0] = fmaf(a1, bits2f(u1.x & 0xffffu), acc[0]);
                acc[1] = fmaf(a1, bits2f(u1.x >> 16),     acc[1]);
                acc[2] = fmaf(a1, bits2f(u1.y & 0xffffu), acc[2]);
                acc[3] = fmaf(a1, bits2f(u1.y >> 16),     acc[3]);
                acc[4] = fmaf(a1, bits2f(u1.z & 0xffffu), acc[4]);
                acc[5] = fmaf(a1, bits2f(u1.z >> 16),     acc[5]);
                acc[6] = fmaf(a1, bits2f(u1.w & 0xffffu), acc[6]);
                acc[7] = fmaf(a1, bits2f(u1.w >> 16),     acc[7]);
            }
        }
        for(; j < jmax; j++){
            int k = 8*j + g;
            float a = __shfl(w_l, k, 64);
            int   s = __shfl(s_l, k, 64);
            if(a != 0.f){
                uint4 u = *(const uint4*)&wh16[(size_t)s*64 + c8];
                acc[0] = fmaf(a, bits2f(u.x & 0xffffu), acc[0]);
                acc[1] = fmaf(a, bits2f(u.x >> 16),     acc[1]);
                acc[2] = fmaf(a, bits2f(u.y & 0xffffu), acc[2]);
                acc[3] = fmaf(a, bits2f(u.y >> 16),     acc[3]);
                acc[4] = fmaf(a, bits2f(u.z & 0xffffu), acc[4]);
                acc[5] = fmaf(a, bits2f(u.z >> 16),     acc[5]);
                acc[6] = fmaf(a, bits2f(u.w & 0xffffu), acc[6]);
                acc[7] = fmaf(a, bits2f(u.w >> 16),     acc[7]);
            }
        }
    }
    #pragma unroll
    for(int off=1; off<64; off<<=1) zl += __shfl_xor(zl, off, 64);
    #pragma unroll
    for(int i=0;i<8;i++){
        acc[i] += __shfl_xor(acc[i], 8, 64);
        acc[i] += __shfl_xor(acc[i], 16, 64);
        acc[i] += __shfl_xor(acc[i], 32, 64);
    }
    if(lane == 0) mz[gw] = make_float2(m, zl);
    if(lane < 8){
        *(float4*)&U[(size_t)gw*64 + c8 + 0] = make_float4(acc[0],acc[1],acc[2],acc[3]);
        *(float4*)&U[(size_t)gw*64 + c8 + 4] = make_float4(acc[4],acc[5],acc[6],acc[7]);
    }
}

// ---------------- node (m,z) -> global (M, 1/Z), two-stage ----------------
__global__ __launch_bounds__(256) void k_mz_part(const float2* __restrict__ mz,
                                                 float2* __restrict__ bmz){
    int tid = blockIdx.x*256 + threadIdx.x;
    int stride = gridDim.x*256;
    float m = SENTINEL, z = 0.f;
    for(int i = tid; i < NODES; i += stride){
        float2 e = mz[i];
        float M = fmaxf(m, e.x);
        z = z*__expf(m - M) + e.y*__expf(e.x - M);
        m = M;
    }
    for(int off=1; off<64; off<<=1){
        float m2 = __shfl_xor(m, off, 64), z2 = __shfl_xor(z, off, 64);
        float M = fmaxf(m, m2);
        z = z*__expf(m - M) + z2*__expf(m2 - M);
        m = M;
    }
    __shared__ float sm[4], sz[4];
    int w = threadIdx.x >> 6;
    if((threadIdx.x & 63) == 0){ sm[w] = m; sz[w] = z; }
    __syncthreads();
    if(threadIdx.x == 0){
        for(int i=1;i<4;i++){
            float M = fmaxf(m, sm[i]);
            z = z*__expf(m - M) + sz[i]*__expf(sm[i] - M);
            m = M;
        }
        bmz[blockIdx.x] = make_float2(m, z);
    }
}

__global__ __launch_bounds__(256) void k_mz_final(const float2* __restrict__ bmz,
                                                  float2* __restrict__ MZ,
                                                  unsigned* __restrict__ smaxk){
    int t = threadIdx.x;
    float m = SENTINEL, z = 0.f;
    for(int i = t; i < MZPB; i += 256){
        float2 e = bmz[i];
        float M = fmaxf(m, e.x);
        z = z*__expf(m - M) + e.y*__expf(e.x - M);
        m = M;
    }
    for(int off=1; off<64; off<<=1){
        float m2 = __shfl_xor(m, off, 64), z2 = __shfl_xor(z, off, 64);
        float M = fmaxf(m, m2);
        z = z*__expf(m - M) + z2*__expf(m2 - M);
        m = M;
    }
    __shared__ float sm[4], sz[4];
    int w = t >> 6;
    if((t & 63) == 0){ sm[w] = m; sz[w] = z; }
    __syncthreads();
    if(t == 0){
        for(int i=1;i<4;i++){
            float M = fmaxf(m, sm[i]);
            z = z*__expf(m - M) + sz[i]*__expf(sm[i] - M);
            m = M;
        }
        MZ[0] = make_float2(m, 1.0f / z);
        smaxk[0] = 0u;   // reset S* accumulator for the next layer
    }
}

// ---------------- fused out-proj + elu + log_softmax, GEMM-tiled (fp32 output).
// Input is unnormalized U2: apply h = elu(U * exp(m_n - M) * invZ) during H-load.
__global__ __launch_bounds__(256) void k_out(const float* __restrict__ h,
    const float2* __restrict__ mzv, const float2* __restrict__ MZg,
    const void* __restrict__ Wo, const void* __restrict__ bo,
    const int* __restrict__ flags, float* __restrict__ out)
{
    __shared__ float Ht[64][65];
    __shared__ float Wsh[64][44];
    __shared__ float logits[64][44];
    __shared__ float rlz[64];
    bool f32 = flags[0] != 0;
    int t = threadIdx.x;
    int block_row = blockIdx.x * 64;

    for(int i = t; i < 64*NCLS; i += 256){
        Wsh[i/NCLS][i%NCLS] = ldin(Wo, i, f32);
    }
    {
        int r_load = t >> 2, q = t & 3;
        int grow = block_row + r_load;
        const float4* hv = (const float4*)h;
        float2 gz = MZg[0];
        float2 nm = (grow < NODES) ? mzv[grow] : make_float2(SENTINEL, 0.f);
        float sA = __expf(nm.x - gz.x) * gz.y;
        #pragma unroll
        for(int i = 0; i < 4; i++){
            int vi = q + 4*i;
            float4 u = make_float4(0.f,0.f,0.f,0.f);
            if(grow < NODES) u = hv[(size_t)grow*16 + vi];
            u.x = elu_fast(u.x*sA); u.y = elu_fast(u.y*sA);
            u.z = elu_fast(u.z*sA); u.w = elu_fast(u.w*sA);
            Ht[vi*4+0][r_load] = u.x; Ht[vi*4+1][r_load] = u.y;
            Ht[vi*4+2][r_load] = u.z; Ht[vi*4+3][r_load] = u.w;
        }
    }
    __syncthreads();

    int cg = t & 15, rg = t >> 4;
    int c0 = cg * 4, r0 = rg * 4;
    if(cg < 10){
        float acc[4][4] = {{0.f,0.f,0.f,0.f},{0.f,0.f,0.f,0.f},{0.f,0.f,0.f,0.f},{0.f,0.f,0.f,0.f}};
        #pragma unroll 8
        for(int k = 0; k < 64; k++){
            float4 a = *(const float4*)&Ht[k][r0];
            float4 w = *(const float4*)&Wsh[k][c0];
            float av4[4] = {a.x,a.y,a.z,a.w};
            float wv4[4] = {w.x,w.y,w.z,w.w};
            #pragma unroll
            for(int i=0;i<4;i++)
                #pragma unroll
                for(int j=0;j<4;j++)
                    acc[i][j] = fmaf(av4[i], wv4[j], acc[i][j]);
        }
        float b[4];
        #pragma unroll
        for(int j=0;j<4;j++) b[j] = ldin(bo, c0+j, f32);
        #pragma unroll
        for(int i=0;i<4;i++)
            #pragma unroll
            for(int j=0;j<4;j++){
                logits[r0+i][c0+j] = elu_fast(acc[i][j] + b[j]);
            }
    }
    __syncthreads();

    {
        int r = t >> 2, qq = t & 3;
        float m = SENTINEL;
        #pragma unroll
        for(int i=0;i<10;i++) m = fmaxf(m, logits[r][qq*10 + i]);
        m = fmaxf(m, __shfl_xor(m, 1, 64));
        m = fmaxf(m, __shfl_xor(m, 2, 64));
        float s = 0.f;
        #pragma unroll
        for(int i=0;i<10;i++) s += __expf(logits[r][qq*10 + i] - m);
        s += __shfl_xor(s, 1, 64);
        s += __shfl_xor(s, 2, 64);
        if(qq == 0) rlz[r] = m + logf(s);
    }
    __syncthreads();

    for(int i = t; i < 64*NCLS; i += 256){
        int rr = i / NCLS, cc = i % NCLS;
        if(block_row + rr < NODES)
            out[(size_t)(block_row)*NCLS + i] = logits[rr][cc] - rlz[rr];
    }
}

extern "C" void kernel_launch(void* const* d_in, const int* in_sizes, int n_in,
                              void* d_out, int out_size, void* d_ws, size_t ws_size,
                              hipStream_t stream)
{
    const void* x      = d_in[0];
    const int*  ei     = (const int*)d_in[1];
    const void* emb_w  = d_in[2];
    const void* emb_b  = d_in[3];
    const void* Ws     = d_in[4];
    const void* attn_a = d_in[5];
    const void* out_w  = d_in[6];
    const void* out_b  = d_in[7];
    float* out = (float*)d_out;

    char* ws = (char*)d_ws;
    size_t off = 0;
    auto alloc = [&](size_t bytes)->char*{
        char* p = ws + off;
        off = (off + bytes + 255) & ~(size_t)255;
        return p;
    };
    int*    flags   = (int*)   alloc(256);
    float*  h       = (float*) alloc((size_t)NODES*HID*4);   // emb out / U1 / U2; aliased as phase-A tmp
    unsigned short* wh16 = (unsigned short*)alloc((size_t)NODES*HID*2);
    float*  ssrc    = (float*) alloc((size_t)NODES*4);
    float*  sdst    = (float*) alloc((size_t)NODES*4);
    int*    rowst   = (int*)   alloc((size_t)(NODES+1)*4);
    int*    col     = (int*)   alloc((size_t)EDGES*4);
    float2* mz      = (float2*)alloc((size_t)NODES*8);
    int*    bdeg    = (int*)   alloc(NBUCK*4);
    int*    bstart  = (int*)   alloc((NBUCK+1)*4);
    int*    bcursor = (int*)   alloc(NBUCK*4);
    float2* bmz     = (float2*)alloc(MZPB*8);
    float2* MZ      = (float2*)alloc(16);
    unsigned* smaxk = (unsigned*)alloc(256);

    int2* tmp = (int2*)h;   // consumed before k_gemm writes h

    k_detect<<<1, 256, 0, stream>>>((const unsigned*)x, (const unsigned*)ei, flags);

    hipMemsetAsync(bdeg, 0, NBUCK*4, stream);
    hipMemsetAsync(smaxk, 0, 4, stream);   // encoded -inf
    k_bhist<<<256, 256, 0, stream>>>(ei, flags, bdeg);
    k_bscan<<<1, 256, 0, stream>>>(bdeg, bstart, bcursor);
    k_bucket_scatter<<<NCHUNK, 256, 0, stream>>>(ei, flags, bcursor, tmp);
    k_bucket_sort<<<NBUCK, 512, 0, stream>>>(tmp, bstart, col, rowst);

    k_gemm<INDIM, 0, true, false, false, 0><<<(NODES+63)/64, 256, 0, stream>>>(
        x, emb_w, 0, emb_b, nullptr, 0, flags, h, nullptr, nullptr, nullptr, nullptr, nullptr);

    // ---- layer 0 ----
    k_gemm<HID, 2, false, true, true, 0><<<(NODES+63)/64, 256, 0, stream>>>(
        h, Ws, 0, nullptr, attn_a, 0, flags, wh16, ssrc, sdst, nullptr, nullptr, smaxk);
    k_aggregate<<<(NODES+3)/4, 256, 0, stream>>>(wh16, rowst, col, ssrc, sdst, smaxk, h, mz);
    k_mz_part <<<MZPB, 256, 0, stream>>>(mz, bmz);
    k_mz_final<<<1, 256, 0, stream>>>(bmz, MZ, smaxk);   // also resets smaxk

    // ---- layer 1: A = U1 with deferred normalization + ELU fused into A-load ----
    k_gemm<HID, 2, false, true, true, 1><<<(NODES+63)/64, 256, 0, stream>>>(
        h, Ws, HID*HID, nullptr, attn_a, 2*HID, flags, wh16, ssrc, sdst, mz, MZ, smaxk);
    k_aggregate<<<(NODES+3)/4, 256, 0, stream>>>(wh16, rowst, col, ssrc, sdst, smaxk, h, mz);
    k_mz_part <<<MZPB, 256, 0, stream>>>(mz, bmz);
    k_mz_final<<<1, 256, 0, stream>>>(bmz, MZ, smaxk);

    k_out<<<(NODES+63)/64, 256, 0, stream>>>(h, mz, MZ, out_w, out_b, flags, out);
}

// Round 5
// 359.203 us; speedup vs baseline: 1.3127x; 1.3127x over previous
//
#include <hip/hip_runtime.h>
#include <hip/hip_bf16.h>

#define NODES   100000
#define EDGES   1600000
#define INDIM   128
#define HID     64
#define NCLS    40
#define NEG_BIG_F (-9000000000000000.0f)
#define SENTINEL  (-3.0e38f)

#define BN       512                 // dst-nodes per coarse bucket (dst >> 9)
#define NBUCK    196                 // ceil(100000/512)
#define CHUNK    7168                // edges per phase-A block
#define NCHUNK   ((EDGES + CHUNK - 1) / CHUNK)   // 224
#define BCAP     8960                // phase-B stage capacity (mean 8192)
#define MZPB     256                 // node-mz partial blocks
#define SMB      128                 // k_smax blocks (1 atomic per block)

static __device__ __forceinline__ float b2f(__hip_bfloat16 h){
    return __bfloat162float(h);
}
static __device__ __forceinline__ float bits2f(unsigned int b){
    union { unsigned int u; float f; } v; v.u = b << 16; return v.f;
}
static __device__ __forceinline__ unsigned short f2b(float f){
    __hip_bfloat16 h = __float2bfloat16(f);
    return *reinterpret_cast<unsigned short*>(&h);
}
static __device__ __forceinline__ float ldin(const void* p, int i, bool f32){
    return f32 ? ((const float*)p)[i] : b2f(((const __hip_bfloat16*)p)[i]);
}
// fast ELU: expm1f is a ~30-instruction libm expansion; __expf(x)-1 is 3 instr,
// abs error ~1e-7 -- irrelevant vs the 7.4e-2 test threshold.
static __device__ __forceinline__ float elu_fast(float x){
    return (x > 0.f) ? x : (__expf(x) - 1.f);
}
// order-preserving float<->uint encoding for atomicMax on floats
static __device__ __forceinline__ unsigned fenc(float f){
    unsigned u = __float_as_uint(f);
    return (u & 0x80000000u) ? ~u : (u | 0x80000000u);
}
static __device__ __forceinline__ float fdec(unsigned k){
    return __uint_as_float((k & 0x80000000u) ? (k & 0x7fffffffu) : ~k);
}
static __device__ __forceinline__ void unpack8(uint4 u, float* o){
    o[0]=bits2f(u.x & 0xffffu); o[1]=bits2f(u.x >> 16);
    o[2]=bits2f(u.y & 0xffffu); o[3]=bits2f(u.y >> 16);
    o[4]=bits2f(u.z & 0xffffu); o[5]=bits2f(u.z >> 16);
    o[6]=bits2f(u.w & 0xffffu); o[7]=bits2f(u.w >> 16);
}
static __device__ __forceinline__ int ld_src(const int* ei, int i, bool i64){
    return i64 ? ei[2*i] : ei[i];
}
static __device__ __forceinline__ int ld_dst(const int* ei, int i, bool i64){
    return i64 ? ei[2*(EDGES + i)] : ei[EDGES + i];
}

// flags[0]=1 if floats are fp32; flags[1]=1 if edge_index is int64
__global__ __launch_bounds__(256) void k_detect(const unsigned* __restrict__ xw,
                                                const unsigned* __restrict__ eiw,
                                                int* __restrict__ flags){
    __shared__ int s1[256], s2[256];
    int t = threadIdx.x;
    int c1 = 0, c2 = 0;
    for(int i = t; i < 1024; i += 256){
        unsigned e = (xw[i] >> 23) & 0xffu;
        c1 += (e >= 90u && e <= 160u) ? 1 : 0;
        c2 += (eiw[2*i + 1] == 0u) ? 1 : 0;
    }
    s1[t] = c1; s2[t] = c2; __syncthreads();
    for(int off = 128; off > 0; off >>= 1){
        if(t < off){ s1[t] += s1[t+off]; s2[t] += s2[t+off]; }
        __syncthreads();
    }
    if(t == 0){ flags[0] = (s1[0] > 512) ? 1 : 0; flags[1] = (s2[0] > 512) ? 1 : 0; }
}

// ---------------- bucket histogram ----------------
__global__ __launch_bounds__(256) void k_bhist(const int* __restrict__ ei,
                                               const int* __restrict__ flags,
                                               int* __restrict__ bdeg){
    __shared__ int sh[NBUCK];
    bool i64 = flags[1] != 0;
    int t = threadIdx.x;
    for(int i = t; i < NBUCK; i += 256) sh[i] = 0;
    __syncthreads();
    int i = blockIdx.x*256 + t;
    int stride = gridDim.x*256;
    for(; i < EDGES; i += stride) atomicAdd(&sh[ld_dst(ei, i, i64) >> 9], 1);
    __syncthreads();
    for(int b = t; b < NBUCK; b += 256) if(sh[b]) atomicAdd(&bdeg[b], sh[b]);
}

// parallel exclusive scan over NBUCK buckets
__global__ __launch_bounds__(256) void k_bscan(const int* __restrict__ bdeg,
                        int* __restrict__ bstart, int* __restrict__ bcursor){
    __shared__ int sh[256];
    int t = threadIdx.x;
    int v = (t < NBUCK) ? bdeg[t] : 0;
    sh[t] = v; __syncthreads();
    for(int off = 1; off < 256; off <<= 1){
        int x = (t >= off) ? sh[t - off] : 0;
        __syncthreads();
        sh[t] += x;
        __syncthreads();
    }
    int excl = sh[t] - v;
    if(t < NBUCK){ bstart[t] = excl; bcursor[t] = excl; }
    if(t == 255) bstart[NBUCK] = sh[255];
}

// ---------------- phase A: LDS-binned coarse scatter ----------------
__global__ __launch_bounds__(256) void k_bucket_scatter(const int* __restrict__ ei,
    const int* __restrict__ flags, int* __restrict__ bcursor, int2* __restrict__ tmp){
    __shared__ int  sCnt[NBUCK], sScan[NBUCK], sCur[NBUCK], sGofs[NBUCK];
    __shared__ int2 stage[CHUNK];
    bool i64 = flags[1] != 0;
    int t = threadIdx.x;
    int base = blockIdx.x * CHUNK;
    int n = EDGES - base; if(n > CHUNK) n = CHUNK; if(n <= 0) return;

    for(int b = t; b < NBUCK; b += 256) sCnt[b] = 0;
    __syncthreads();
    for(int j = t; j < n; j += 256)
        atomicAdd(&sCnt[ld_dst(ei, base + j, i64) >> 9], 1);
    __syncthreads();
    for(int b = t; b < NBUCK; b += 256) sScan[b] = sCnt[b];
    __syncthreads();
    for(int off = 1; off < NBUCK; off <<= 1){
        int v = 0;
        if(t < NBUCK && t >= off) v = sScan[t - off];
        __syncthreads();
        if(t < NBUCK) sScan[t] += v;
        __syncthreads();
    }
    if(t < NBUCK){
        int excl = sScan[t] - sCnt[t];
        sCur[t]  = excl;
        sGofs[t] = sCnt[t] ? atomicAdd(&bcursor[t], sCnt[t]) : 0;
    }
    __syncthreads();
    for(int j = t; j < n; j += 256){
        int src = ld_src(ei, base + j, i64);
        int dst = ld_dst(ei, base + j, i64);
        int pos = atomicAdd(&sCur[dst >> 9], 1);
        stage[pos] = make_int2(src, dst);
    }
    __syncthreads();
    for(int i = t; i < n; i += 256){
        int2 e = stage[i];
        int  b = e.y >> 9;
        int  excl = sScan[b] - sCnt[b];
        tmp[(size_t)sGofs[b] + (i - excl)] = e;
    }
}

// ---------------- phase B: per-bucket counting sort -> col + rowst ----------------
__global__ __launch_bounds__(512) void k_bucket_sort(const int2* __restrict__ tmp,
    const int* __restrict__ bstart, int* __restrict__ col,
    int* __restrict__ rowst){
    __shared__ int  sCnt[BN], sScan[BN], sCur[BN];
    __shared__ int2 stage[BCAP];
    int b = blockIdx.x, t = threadIdx.x;
    int nb0 = b * BN;
    int gbase = bstart[b], gend = bstart[b+1];
    int cnt = gend - gbase;

    if(t < BN) sCnt[t] = 0;
    __syncthreads();
    for(int j = gbase + t; j < gend; j += 512)
        atomicAdd(&sCnt[tmp[j].y - nb0], 1);
    __syncthreads();
    if(t < BN) sScan[t] = sCnt[t];
    __syncthreads();
    for(int off = 1; off < BN; off <<= 1){
        int v = 0;
        if(t < BN && t >= off) v = sScan[t - off];
        __syncthreads();
        if(t < BN) sScan[t] += v;
        __syncthreads();
    }
    if(t < BN) sCur[t] = sScan[t] - sCnt[t];
    if(t < BN && (nb0 + t) < NODES) rowst[nb0 + t] = gbase + (sScan[t] - sCnt[t]);
    if(b == 0 && t == 0) rowst[NODES] = EDGES;
    __syncthreads();
    for(int j = gbase + t; j < gend; j += 512){
        int2 e = tmp[j];
        int pos = atomicAdd(&sCur[e.y - nb0], 1);
        if(pos < BCAP) stage[pos] = e;
        else col[gbase + pos] = e.x;
    }
    __syncthreads();
    int lim = (cnt < BCAP) ? cnt : BCAP;
    for(int i = t; i < lim; i += 512)
        col[gbase + i] = stage[i].x;
}

// ---------------- GEMM: C[N x 64] = A[N x K] * W[K x 64] (+bias) (+score epilogue)
// SCALEA=1: A rows are unnormalized aggregates U; apply h = elu(U * exp(m_n - M) * invZ)
// during the A-load. NOTE: no atomics in the epilogue -- Round-4 showed one atomicMax
// per wave to a single address costs ~60us/dispatch (same-address RMW serialization).
template<int K, int AMODE, bool WITH_BIAS, bool WITH_SCORES, bool CBF16, int SCALEA>
__global__ __launch_bounds__(256) void k_gemm(
    const void* __restrict__ Aptr,
    const void* __restrict__ Wb,   int woff,
    const void* __restrict__ biasb,
    const void* __restrict__ attnb, int aoff,
    const int*  __restrict__ flags,
    void* __restrict__ Cout,
    float* __restrict__ s_src,
    float* __restrict__ s_dst,
    const float2* __restrict__ mzv,
    const float2* __restrict__ MZg)
{
    __shared__ float At[64][68];
    __shared__ float Wf[64][64];
    const bool wf32 = flags[0] != 0;
    const bool af32 = (AMODE == 2) ? true : wf32;
    const int t = threadIdx.x;
    const int block_row = blockIdx.x * 64;
    const int r_load = t >> 2;
    const int q_load = t & 3;
    const int grow_load = block_row + r_load;

    const int c0 = (t & 15) * 4;
    const int r0 = (t >> 4) * 4;

    float sA = 1.f;
    if constexpr (SCALEA == 1){
        float2 gz = MZg[0];
        float2 nm = (grow_load < NODES) ? mzv[grow_load] : make_float2(SENTINEL, 0.f);
        sA = __expf(nm.x - gz.x) * gz.y;
    }

    float acc[4][4] = {{0.f,0.f,0.f,0.f},{0.f,0.f,0.f,0.f},{0.f,0.f,0.f,0.f},{0.f,0.f,0.f,0.f}};

    for(int kb = 0; kb < K; kb += 64){
        if(wf32){
            const float4* wv = (const float4*)Wb;
            for(int v = t; v < 1024; v += 256){
                float4 u = wv[(size_t)(woff + kb*64)/4 + v];
                int f = v*4; int k = f >> 6; int c = f & 63;
                Wf[k][c]=u.x; Wf[k][c+1]=u.y; Wf[k][c+2]=u.z; Wf[k][c+3]=u.w;
            }
        } else {
            const uint4* wv = (const uint4*)Wb;
            for(int v = t; v < 512; v += 256){
                uint4 u = wv[(size_t)(woff + kb*64)/8 + v];
                float o[8]; unpack8(u, o);
                int f = v*8; int k = f >> 6; int c = f & 63;
                #pragma unroll
                for(int j=0;j<8;j++) Wf[k][c+j] = o[j];
            }
        }
        if(af32){
            const float4* av = (const float4*)Aptr;
            #pragma unroll
            for(int i=0;i<4;i++){
                int vi = q_load + 4*i;
                int k0 = vi*4;
                float4 u = make_float4(0.f,0.f,0.f,0.f);
                if(grow_load < NODES) u = av[(size_t)grow_load*(K/4) + (kb>>2) + vi];
                if constexpr (SCALEA == 1){
                    u.x = elu_fast(u.x*sA); u.y = elu_fast(u.y*sA);
                    u.z = elu_fast(u.z*sA); u.w = elu_fast(u.w*sA);
                }
                At[k0+0][r_load]=u.x; At[k0+1][r_load]=u.y;
                At[k0+2][r_load]=u.z; At[k0+3][r_load]=u.w;
            }
        } else {
            const uint4* av = (const uint4*)Aptr;
            #pragma unroll
            for(int i=0;i<2;i++){
                int vi = q_load + 4*i;
                int k0 = vi*8;
                float o[8];
                if(grow_load < NODES){
                    uint4 u = av[(size_t)grow_load*(K/8) + (kb>>3) + vi];
                    unpack8(u, o);
                } else {
                    #pragma unroll
                    for(int j=0;j<8;j++) o[j]=0.f;
                }
                #pragma unroll
                for(int j=0;j<8;j++) At[k0+j][r_load] = o[j];
            }
        }
        __syncthreads();
        #pragma unroll 8
        for(int k=0;k<64;k++){
            float4 a = *(const float4*)&At[k][r0];
            float4 w = *(const float4*)&Wf[k][c0];
            float av4[4] = {a.x,a.y,a.z,a.w};
            float wv4[4] = {w.x,w.y,w.z,w.w};
            #pragma unroll
            for(int i=0;i<4;i++)
                #pragma unroll
                for(int j=0;j<4;j++)
                    acc[i][j] = fmaf(av4[i], wv4[j], acc[i][j]);
        }
        __syncthreads();
    }

    float bias[4] = {0.f,0.f,0.f,0.f};
    if constexpr (WITH_BIAS){
        #pragma unroll
        for(int j=0;j<4;j++) bias[j] = ldin(biasb, c0+j, wf32);
    }
    #pragma unroll
    for(int i=0;i<4;i++){
        int grow = block_row + r0 + i;
        if(grow < NODES){
            if constexpr (CBF16){
                ushort4 o;
                o.x = f2b(acc[i][0]+bias[0]); o.y = f2b(acc[i][1]+bias[1]);
                o.z = f2b(acc[i][2]+bias[2]); o.w = f2b(acc[i][3]+bias[3]);
                *(ushort4*)((unsigned short*)Cout + (size_t)grow*64 + c0) = o;
            } else {
                float4 o = make_float4(acc[i][0]+bias[0], acc[i][1]+bias[1],
                                       acc[i][2]+bias[2], acc[i][3]+bias[3]);
                *(float4*)((float*)Cout + (size_t)grow*64 + c0) = o;
            }
        }
    }
    if constexpr (WITH_SCORES){
        float as[4], ad[4];
        #pragma unroll
        for(int j=0;j<4;j++){
            as[j] = ldin(attnb, aoff + c0+j, wf32);
            ad[j] = ldin(attnb, aoff + 64+c0+j, wf32);
        }
        #pragma unroll
        for(int i=0;i<4;i++){
            float ps = 0.f, pd = 0.f;
            #pragma unroll
            for(int j=0;j<4;j++){ ps = fmaf(acc[i][j], as[j], ps); pd = fmaf(acc[i][j], ad[j], pd); }
            for(int off=1; off<16; off<<=1){
                ps += __shfl_xor(ps, off, 64);
                pd += __shfl_xor(pd, off, 64);
            }
            int grow = block_row + r0 + i;
            if((t & 15) == 0 && grow < NODES){ s_src[grow] = ps; s_dst[grow] = pd; }
        }
    }
}

// ---------------- S* = max over nodes of ssrc: grid-stride, 1 atomic per BLOCK ----
__global__ __launch_bounds__(256) void k_smax(const float* __restrict__ ssrc,
                                              unsigned* __restrict__ smaxk){
    int tid = blockIdx.x*256 + threadIdx.x;
    int stride = gridDim.x*256;
    float m = SENTINEL;
    for(int i = tid; i < NODES; i += stride) m = fmaxf(m, ssrc[i]);
    #pragma unroll
    for(int off=1; off<64; off<<=1) m = fmaxf(m, __shfl_xor(m, off, 64));
    __shared__ float sm[4];
    int w = threadIdx.x >> 6;
    if((threadIdx.x & 63) == 0) sm[w] = m;
    __syncthreads();
    if(threadIdx.x == 0){
        for(int i=1;i<4;i++) m = fmaxf(m, sm[i]);
        atomicMax(smaxk, fenc(m));
    }
}

// ---------------- fused aggregate: fixed wave-uniform shift m_n = S* + sdst[n]
// (S* = global max ssrc, from k_smax). att = ssrc[col]+sdst[n] <= m_n always,
// so w = exp(att - m_n) needs NO online max / rescale -- inner loop identical to the
// known-good Round-2 structure. Emits unnormalized U_n and (m_n, z_n); global
// normalization exp(m_n - M)/Z applied by the next consumer. Masked edges (v<=0)
// get att = NEG_BIG -> w = 0 exactly (matches reference underflow behavior).
__global__ __launch_bounds__(256) void k_aggregate(const unsigned short* __restrict__ wh16,
    const int* __restrict__ row_start, const int* __restrict__ col,
    const float* __restrict__ ssrc, const float* __restrict__ sdst,
    const unsigned* __restrict__ smaxk,
    float* __restrict__ U, float2* __restrict__ mz)
{
    int gw = (blockIdx.x*256 + threadIdx.x) >> 6;
    int lane = threadIdx.x & 63;
    if(gw >= NODES) return;
    int beg = row_start[gw], end = row_start[gw+1];
    int g  = lane >> 3;           // edge-group 0..7
    int c8 = (lane & 7) * 8;      // feature slice base
    float sdn = sdst[gw];
    const float m = fdec(*smaxk) + sdn;   // wave-uniform upper bound of att
    float zl = 0.f;
    float acc[8] = {0.f,0.f,0.f,0.f,0.f,0.f,0.f,0.f};
    for(int base = beg; base < end; base += 64){
        int idx = base + lane;
        bool vld = idx < end;
        int   s_l = vld ? col[idx] : 0;
        float v   = ssrc[s_l] + sdn;                 // hot 400KB gather
        float att = (vld && v > 0.f) ? v : NEG_BIG_F;
        float w_l = __expf(att - m);                 // in (0,1]; exactly 0 for masked
        zl += w_l;
        int n = end - base; if(n > 64) n = 64;
        int jmax = (n + 7) >> 3;
        int j = 0;
        for(; j + 2 <= jmax; j += 2){
            int k0 = 8*j + g, k1 = k0 + 8;
            float a0 = __shfl(w_l, k0, 64); int s0 = __shfl(s_l, k0, 64);
            float a1 = __shfl(w_l, k1, 64); int s1 = __shfl(s_l, k1, 64);
            bool p0 = (a0 != 0.f), p1 = (a1 != 0.f);
            uint4 u0, u1;
            if(p0) u0 = *(const uint4*)&wh16[(size_t)s0*64 + c8];
            if(p1) u1 = *(const uint4*)&wh16[(size_t)s1*64 + c8];
            if(p0){
                acc[0] = fmaf(a0, bits2f(u0.x & 0xffffu), acc[0]);
                acc[1] = fmaf(a0, bits2f(u0.x >> 16),     acc[1]);
                acc[2] = fmaf(a0, bits2f(u0.y & 0xffffu), acc[2]);
                acc[3] = fmaf(a0, bits2f(u0.y >> 16),     acc[3]);
                acc[4] = fmaf(a0, bits2f(u0.z & 0xffffu), acc[4]);
                acc[5] = fmaf(a0, bits2f(u0.z >> 16),     acc[5]);
                acc[6] = fmaf(a0, bits2f(u0.w & 0xffffu), acc[6]);
                acc[7] = fmaf(a0, bits2f(u0.w >> 16),     acc[7]);
            }
            if(p1){
                acc[0] = fmaf(a1, bits2f(u1.x & 0xffffu), acc[0]);
                acc[1] = fmaf(a1, bits2f(u1.x >> 16),     acc[1]);
                acc[2] = fmaf(a1, bits2f(u1.y & 0xffffu), acc[2]);
                acc[3] = fmaf(a1, bits2f(u1.y >> 16),     acc[3]);
                acc[4] = fmaf(a1, bits2f(u1.z & 0xffffu), acc[4]);
                acc[5] = fmaf(a1, bits2f(u1.z >> 16),     acc[5]);
                acc[6] = fmaf(a1, bits2f(u1.w & 0xffffu), acc[6]);
                acc[7] = fmaf(a1, bits2f(u1.w >> 16),     acc[7]);
            }
        }
        for(; j < jmax; j++){
            int k = 8*j + g;
            float a = __shfl(w_l, k, 64);
            int   s = __shfl(s_l, k, 64);
            if(a != 0.f){
                uint4 u = *(const uint4*)&wh16[(size_t)s*64 + c8];
                acc[0] = fmaf(a, bits2f(u.x & 0xffffu), acc[0]);
                acc[1] = fmaf(a, bits2f(u.x >> 16),     acc[1]);
                acc[2] = fmaf(a, bits2f(u.y & 0xffffu), acc[2]);
                acc[3] = fmaf(a, bits2f(u.y >> 16),     acc[3]);
                acc[4] = fmaf(a, bits2f(u.z & 0xffffu), acc[4]);
                acc[5] = fmaf(a, bits2f(u.z >> 16),     acc[5]);
                acc[6] = fmaf(a, bits2f(u.w & 0xffffu), acc[6]);
                acc[7] = fmaf(a, bits2f(u.w >> 16),     acc[7]);
            }
        }
    }
    #pragma unroll
    for(int off=1; off<64; off<<=1) zl += __shfl_xor(zl, off, 64);
    #pragma unroll
    for(int i=0;i<8;i++){
        acc[i] += __shfl_xor(acc[i], 8, 64);
        acc[i] += __shfl_xor(acc[i], 16, 64);
        acc[i] += __shfl_xor(acc[i], 32, 64);
    }
    if(lane == 0) mz[gw] = make_float2(m, zl);
    if(lane < 8){
        *(float4*)&U[(size_t)gw*64 + c8 + 0] = make_float4(acc[0],acc[1],acc[2],acc[3]);
        *(float4*)&U[(size_t)gw*64 + c8 + 4] = make_float4(acc[4],acc[5],acc[6],acc[7]);
    }
}

// ---------------- node (m,z) -> global (M, 1/Z), two-stage ----------------
__global__ __launch_bounds__(256) void k_mz_part(const float2* __restrict__ mz,
                                                 float2* __restrict__ bmz){
    int tid = blockIdx.x*256 + threadIdx.x;
    int stride = gridDim.x*256;
    float m = SENTINEL, z = 0.f;
    for(int i = tid; i < NODES; i += stride){
        float2 e = mz[i];
        float M = fmaxf(m, e.x);
        z = z*__expf(m - M) + e.y*__expf(e.x - M);
        m = M;
    }
    for(int off=1; off<64; off<<=1){
        float m2 = __shfl_xor(m, off, 64), z2 = __shfl_xor(z, off, 64);
        float M = fmaxf(m, m2);
        z = z*__expf(m - M) + z2*__expf(m2 - M);
        m = M;
    }
    __shared__ float sm[4], sz[4];
    int w = threadIdx.x >> 6;
    if((threadIdx.x & 63) == 0){ sm[w] = m; sz[w] = z; }
    __syncthreads();
    if(threadIdx.x == 0){
        for(int i=1;i<4;i++){
            float M = fmaxf(m, sm[i]);
            z = z*__expf(m - M) + sz[i]*__expf(sm[i] - M);
            m = M;
        }
        bmz[blockIdx.x] = make_float2(m, z);
    }
}

__global__ __launch_bounds__(256) void k_mz_final(const float2* __restrict__ bmz,
                                                  float2* __restrict__ MZ,
                                                  unsigned* __restrict__ smaxk){
    int t = threadIdx.x;
    float m = SENTINEL, z = 0.f;
    for(int i = t; i < MZPB; i += 256){
        float2 e = bmz[i];
        float M = fmaxf(m, e.x);
        z = z*__expf(m - M) + e.y*__expf(e.x - M);
        m = M;
    }
    for(int off=1; off<64; off<<=1){
        float m2 = __shfl_xor(m, off, 64), z2 = __shfl_xor(z, off, 64);
        float M = fmaxf(m, m2);
        z = z*__expf(m - M) + z2*__expf(m2 - M);
        m = M;
    }
    __shared__ float sm[4], sz[4];
    int w = t >> 6;
    if((t & 63) == 0){ sm[w] = m; sz[w] = z; }
    __syncthreads();
    if(t == 0){
        for(int i=1;i<4;i++){
            float M = fmaxf(m, sm[i]);
            z = z*__expf(m - M) + sz[i]*__expf(sm[i] - M);
            m = M;
        }
        MZ[0] = make_float2(m, 1.0f / z);
        smaxk[0] = 0u;   // reset S* accumulator for the next layer
    }
}

// ---------------- fused out-proj + elu + log_softmax, GEMM-tiled (fp32 output).
// Input is unnormalized U2: apply h = elu(U * exp(m_n - M) * invZ) during H-load.
__global__ __launch_bounds__(256) void k_out(const float* __restrict__ h,
    const float2* __restrict__ mzv, const float2* __restrict__ MZg,
    const void* __restrict__ Wo, const void* __restrict__ bo,
    const int* __restrict__ flags, float* __restrict__ out)
{
    __shared__ float Ht[64][65];
    __shared__ float Wsh[64][44];
    __shared__ float logits[64][44];
    __shared__ float rlz[64];
    bool f32 = flags[0] != 0;
    int t = threadIdx.x;
    int block_row = blockIdx.x * 64;

    for(int i = t; i < 64*NCLS; i += 256){
        Wsh[i/NCLS][i%NCLS] = ldin(Wo, i, f32);
    }
    {
        int r_load = t >> 2, q = t & 3;
        int grow = block_row + r_load;
        const float4* hv = (const float4*)h;
        float2 gz = MZg[0];
        float2 nm = (grow < NODES) ? mzv[grow] : make_float2(SENTINEL, 0.f);
        float sA = __expf(nm.x - gz.x) * gz.y;
        #pragma unroll
        for(int i = 0; i < 4; i++){
            int vi = q + 4*i;
            float4 u = make_float4(0.f,0.f,0.f,0.f);
            if(grow < NODES) u = hv[(size_t)grow*16 + vi];
            u.x = elu_fast(u.x*sA); u.y = elu_fast(u.y*sA);
            u.z = elu_fast(u.z*sA); u.w = elu_fast(u.w*sA);
            Ht[vi*4+0][r_load] = u.x; Ht[vi*4+1][r_load] = u.y;
            Ht[vi*4+2][r_load] = u.z; Ht[vi*4+3][r_load] = u.w;
        }
    }
    __syncthreads();

    int cg = t & 15, rg = t >> 4;
    int c0 = cg * 4, r0 = rg * 4;
    if(cg < 10){
        float acc[4][4] = {{0.f,0.f,0.f,0.f},{0.f,0.f,0.f,0.f},{0.f,0.f,0.f,0.f},{0.f,0.f,0.f,0.f}};
        #pragma unroll 8
        for(int k = 0; k < 64; k++){
            float4 a = *(const float4*)&Ht[k][r0];
            float4 w = *(const float4*)&Wsh[k][c0];
            float av4[4] = {a.x,a.y,a.z,a.w};
            float wv4[4] = {w.x,w.y,w.z,w.w};
            #pragma unroll
            for(int i=0;i<4;i++)
                #pragma unroll
                for(int j=0;j<4;j++)
                    acc[i][j] = fmaf(av4[i], wv4[j], acc[i][j]);
        }
        float b[4];
        #pragma unroll
        for(int j=0;j<4;j++) b[j] = ldin(bo, c0+j, f32);
        #pragma unroll
        for(int i=0;i<4;i++)
            #pragma unroll
            for(int j=0;j<4;j++){
                logits[r0+i][c0+j] = elu_fast(acc[i][j] + b[j]);
            }
    }
    __syncthreads();

    {
        int r = t >> 2, qq = t & 3;
        float m = SENTINEL;
        #pragma unroll
        for(int i=0;i<10;i++) m = fmaxf(m, logits[r][qq*10 + i]);
        m = fmaxf(m, __shfl_xor(m, 1, 64));
        m = fmaxf(m, __shfl_xor(m, 2, 64));
        float s = 0.f;
        #pragma unroll
        for(int i=0;i<10;i++) s += __expf(logits[r][qq*10 + i] - m);
        s += __shfl_xor(s, 1, 64);
        s += __shfl_xor(s, 2, 64);
        if(qq == 0) rlz[r] = m + logf(s);
    }
    __syncthreads();

    for(int i = t; i < 64*NCLS; i += 256){
        int rr = i / NCLS, cc = i % NCLS;
        if(block_row + rr < NODES)
            out[(size_t)(block_row)*NCLS + i] = logits[rr][cc] - rlz[rr];
    }
}

extern "C" void kernel_launch(void* const* d_in, const int* in_sizes, int n_in,
                              void* d_out, int out_size, void* d_ws, size_t ws_size,
                              hipStream_t stream)
{
    const void* x      = d_in[0];
    const int*  ei     = (const int*)d_in[1];
    const void* emb_w  = d_in[2];
    const void* emb_b  = d_in[3];
    const void* Ws     = d_in[4];
    const void* attn_a = d_in[5];
    const void* out_w  = d_in[6];
    const void* out_b  = d_in[7];
    float* out = (float*)d_out;

    char* ws = (char*)d_ws;
    size_t off = 0;
    auto alloc = [&](size_t bytes)->char*{
        char* p = ws + off;
        off = (off + bytes + 255) & ~(size_t)255;
        return p;
    };
    int*    flags   = (int*)   alloc(256);
    float*  h       = (float*) alloc((size_t)NODES*HID*4);   // emb out / U1 / U2; aliased as phase-A tmp
    unsigned short* wh16 = (unsigned short*)alloc((size_t)NODES*HID*2);
    float*  ssrc    = (float*) alloc((size_t)NODES*4);
    float*  sdst    = (float*) alloc((size_t)NODES*4);
    int*    rowst   = (int*)   alloc((size_t)(NODES+1)*4);
    int*    col     = (int*)   alloc((size_t)EDGES*4);
    float2* mz      = (float2*)alloc((size_t)NODES*8);
    int*    bdeg    = (int*)   alloc(NBUCK*4);
    int*    bstart  = (int*)   alloc((NBUCK+1)*4);
    int*    bcursor = (int*)   alloc(NBUCK*4);
    float2* bmz     = (float2*)alloc(MZPB*8);
    float2* MZ      = (float2*)alloc(16);
    unsigned* smaxk = (unsigned*)alloc(256);

    int2* tmp = (int2*)h;   // consumed before k_gemm writes h

    k_detect<<<1, 256, 0, stream>>>((const unsigned*)x, (const unsigned*)ei, flags);

    hipMemsetAsync(bdeg, 0, NBUCK*4, stream);
    hipMemsetAsync(smaxk, 0, 4, stream);   // encoded -inf
    k_bhist<<<256, 256, 0, stream>>>(ei, flags, bdeg);
    k_bscan<<<1, 256, 0, stream>>>(bdeg, bstart, bcursor);
    k_bucket_scatter<<<NCHUNK, 256, 0, stream>>>(ei, flags, bcursor, tmp);
    k_bucket_sort<<<NBUCK, 512, 0, stream>>>(tmp, bstart, col, rowst);

    k_gemm<INDIM, 0, true, false, false, 0><<<(NODES+63)/64, 256, 0, stream>>>(
        x, emb_w, 0, emb_b, nullptr, 0, flags, h, nullptr, nullptr, nullptr, nullptr);

    // ---- layer 0 ----
    k_gemm<HID, 2, false, true, true, 0><<<(NODES+63)/64, 256, 0, stream>>>(
        h, Ws, 0, nullptr, attn_a, 0, flags, wh16, ssrc, sdst, nullptr, nullptr);
    k_smax<<<SMB, 256, 0, stream>>>(ssrc, smaxk);
    k_aggregate<<<(NODES+3)/4, 256, 0, stream>>>(wh16, rowst, col, ssrc, sdst, smaxk, h, mz);
    k_mz_part <<<MZPB, 256, 0, stream>>>(mz, bmz);
    k_mz_final<<<1, 256, 0, stream>>>(bmz, MZ, smaxk);   // also resets smaxk

    // ---- layer 1: A = U1 with deferred normalization + ELU fused into A-load ----
    k_gemm<HID, 2, false, true, true, 1><<<(NODES+63)/64, 256, 0, stream>>>(
        h, Ws, HID*HID, nullptr, attn_a, 2*HID, flags, wh16, ssrc, sdst, mz, MZ);
    k_smax<<<SMB, 256, 0, stream>>>(ssrc, smaxk);
    k_aggregate<<<(NODES+3)/4, 256, 0, stream>>>(wh16, rowst, col, ssrc, sdst, smaxk, h, mz);
    k_mz_part <<<MZPB, 256, 0, stream>>>(mz, bmz);
    k_mz_final<<<1, 256, 0, stream>>>(bmz, MZ, smaxk);

    k_out<<<(NODES+63)/64, 256, 0, stream>>>(h, mz, MZ, out_w, out_b, flags, out);
}

// Round 6
// 332.807 us; speedup vs baseline: 1.4168x; 1.0793x over previous
//
#include <hip/hip_runtime.h>
#include <hip/hip_bf16.h>

#define NODES   100000
#define EDGES   1600000
#define INDIM   128
#define HID     64
#define NCLS    40
#define NEG_BIG_F (-9000000000000000.0f)
#define SENTINEL  (-3.0e38f)

#define BN       512                 // dst-nodes per coarse bucket (dst >> 9)
#define NBUCK    196                 // ceil(100000/512)
#define CHUNK    7168                // edges per phase-A block
#define NCHUNK   ((EDGES + CHUNK - 1) / CHUNK)   // 224
#define BCAP     8960                // phase-B stage capacity (mean 8192)
#define MZPB     256                 // node-mz partial blocks
#define SMB      128                 // k_smax blocks (1 atomic per block)

static __device__ __forceinline__ float b2f(__hip_bfloat16 h){
    return __bfloat162float(h);
}
static __device__ __forceinline__ float bits2f(unsigned int b){
    union { unsigned int u; float f; } v; v.u = b << 16; return v.f;
}
static __device__ __forceinline__ unsigned short f2b(float f){
    __hip_bfloat16 h = __float2bfloat16(f);
    return *reinterpret_cast<unsigned short*>(&h);
}
static __device__ __forceinline__ float ldin(const void* p, int i, bool f32){
    return f32 ? ((const float*)p)[i] : b2f(((const __hip_bfloat16*)p)[i]);
}
// fast ELU: expm1f is a ~30-instruction libm expansion; __expf(x)-1 is 3 instr,
// abs error ~1e-7 -- irrelevant vs the 7.4e-2 test threshold.
static __device__ __forceinline__ float elu_fast(float x){
    return (x > 0.f) ? x : (__expf(x) - 1.f);
}
// order-preserving float<->uint encoding for atomicMax on floats
static __device__ __forceinline__ unsigned fenc(float f){
    unsigned u = __float_as_uint(f);
    return (u & 0x80000000u) ? ~u : (u | 0x80000000u);
}
static __device__ __forceinline__ float fdec(unsigned k){
    return __uint_as_float((k & 0x80000000u) ? (k & 0x7fffffffu) : ~k);
}
static __device__ __forceinline__ void unpack8(uint4 u, float* o){
    o[0]=bits2f(u.x & 0xffffu); o[1]=bits2f(u.x >> 16);
    o[2]=bits2f(u.y & 0xffffu); o[3]=bits2f(u.y >> 16);
    o[4]=bits2f(u.z & 0xffffu); o[5]=bits2f(u.z >> 16);
    o[6]=bits2f(u.w & 0xffffu); o[7]=bits2f(u.w >> 16);
}
static __device__ __forceinline__ int ld_src(const int* ei, int i, bool i64){
    return i64 ? ei[2*i] : ei[i];
}
static __device__ __forceinline__ int ld_dst(const int* ei, int i, bool i64){
    return i64 ? ei[2*(EDGES + i)] : ei[EDGES + i];
}

// flags[0]=1 if floats are fp32; flags[1]=1 if edge_index is int64
__global__ __launch_bounds__(256) void k_detect(const unsigned* __restrict__ xw,
                                                const unsigned* __restrict__ eiw,
                                                int* __restrict__ flags){
    __shared__ int s1[256], s2[256];
    int t = threadIdx.x;
    int c1 = 0, c2 = 0;
    for(int i = t; i < 1024; i += 256){
        unsigned e = (xw[i] >> 23) & 0xffu;
        c1 += (e >= 90u && e <= 160u) ? 1 : 0;
        c2 += (eiw[2*i + 1] == 0u) ? 1 : 0;
    }
    s1[t] = c1; s2[t] = c2; __syncthreads();
    for(int off = 128; off > 0; off >>= 1){
        if(t < off){ s1[t] += s1[t+off]; s2[t] += s2[t+off]; }
        __syncthreads();
    }
    if(t == 0){ flags[0] = (s1[0] > 512) ? 1 : 0; flags[1] = (s2[0] > 512) ? 1 : 0; }
}

// ---------------- bucket histogram ----------------
__global__ __launch_bounds__(256) void k_bhist(const int* __restrict__ ei,
                                               const int* __restrict__ flags,
                                               int* __restrict__ bdeg){
    __shared__ int sh[NBUCK];
    bool i64 = flags[1] != 0;
    int t = threadIdx.x;
    for(int i = t; i < NBUCK; i += 256) sh[i] = 0;
    __syncthreads();
    int i = blockIdx.x*256 + t;
    int stride = gridDim.x*256;
    for(; i < EDGES; i += stride) atomicAdd(&sh[ld_dst(ei, i, i64) >> 9], 1);
    __syncthreads();
    for(int b = t; b < NBUCK; b += 256) if(sh[b]) atomicAdd(&bdeg[b], sh[b]);
}

// parallel exclusive scan over NBUCK buckets
__global__ __launch_bounds__(256) void k_bscan(const int* __restrict__ bdeg,
                        int* __restrict__ bstart, int* __restrict__ bcursor){
    __shared__ int sh[256];
    int t = threadIdx.x;
    int v = (t < NBUCK) ? bdeg[t] : 0;
    sh[t] = v; __syncthreads();
    for(int off = 1; off < 256; off <<= 1){
        int x = (t >= off) ? sh[t - off] : 0;
        __syncthreads();
        sh[t] += x;
        __syncthreads();
    }
    int excl = sh[t] - v;
    if(t < NBUCK){ bstart[t] = excl; bcursor[t] = excl; }
    if(t == 255) bstart[NBUCK] = sh[255];
}

// ---------------- phase A: LDS-binned coarse scatter ----------------
__global__ __launch_bounds__(256) void k_bucket_scatter(const int* __restrict__ ei,
    const int* __restrict__ flags, int* __restrict__ bcursor, int2* __restrict__ tmp){
    __shared__ int  sCnt[NBUCK], sScan[NBUCK], sCur[NBUCK], sGofs[NBUCK];
    __shared__ int2 stage[CHUNK];
    bool i64 = flags[1] != 0;
    int t = threadIdx.x;
    int base = blockIdx.x * CHUNK;
    int n = EDGES - base; if(n > CHUNK) n = CHUNK; if(n <= 0) return;

    for(int b = t; b < NBUCK; b += 256) sCnt[b] = 0;
    __syncthreads();
    for(int j = t; j < n; j += 256)
        atomicAdd(&sCnt[ld_dst(ei, base + j, i64) >> 9], 1);
    __syncthreads();
    for(int b = t; b < NBUCK; b += 256) sScan[b] = sCnt[b];
    __syncthreads();
    for(int off = 1; off < NBUCK; off <<= 1){
        int v = 0;
        if(t < NBUCK && t >= off) v = sScan[t - off];
        __syncthreads();
        if(t < NBUCK) sScan[t] += v;
        __syncthreads();
    }
    if(t < NBUCK){
        int excl = sScan[t] - sCnt[t];
        sCur[t]  = excl;
        sGofs[t] = sCnt[t] ? atomicAdd(&bcursor[t], sCnt[t]) : 0;
    }
    __syncthreads();
    for(int j = t; j < n; j += 256){
        int src = ld_src(ei, base + j, i64);
        int dst = ld_dst(ei, base + j, i64);
        int pos = atomicAdd(&sCur[dst >> 9], 1);
        stage[pos] = make_int2(src, dst);
    }
    __syncthreads();
    for(int i = t; i < n; i += 256){
        int2 e = stage[i];
        int  b = e.y >> 9;
        int  excl = sScan[b] - sCnt[b];
        tmp[(size_t)sGofs[b] + (i - excl)] = e;
    }
}

// ---------------- phase B: per-bucket counting sort -> col + rowst ----------------
__global__ __launch_bounds__(512) void k_bucket_sort(const int2* __restrict__ tmp,
    const int* __restrict__ bstart, int* __restrict__ col,
    int* __restrict__ rowst){
    __shared__ int  sCnt[BN], sScan[BN], sCur[BN];
    __shared__ int2 stage[BCAP];
    int b = blockIdx.x, t = threadIdx.x;
    int nb0 = b * BN;
    int gbase = bstart[b], gend = bstart[b+1];
    int cnt = gend - gbase;

    if(t < BN) sCnt[t] = 0;
    __syncthreads();
    for(int j = gbase + t; j < gend; j += 512)
        atomicAdd(&sCnt[tmp[j].y - nb0], 1);
    __syncthreads();
    if(t < BN) sScan[t] = sCnt[t];
    __syncthreads();
    for(int off = 1; off < BN; off <<= 1){
        int v = 0;
        if(t < BN && t >= off) v = sScan[t - off];
        __syncthreads();
        if(t < BN) sScan[t] += v;
        __syncthreads();
    }
    if(t < BN) sCur[t] = sScan[t] - sCnt[t];
    if(t < BN && (nb0 + t) < NODES) rowst[nb0 + t] = gbase + (sScan[t] - sCnt[t]);
    if(b == 0 && t == 0) rowst[NODES] = EDGES;
    __syncthreads();
    for(int j = gbase + t; j < gend; j += 512){
        int2 e = tmp[j];
        int pos = atomicAdd(&sCur[e.y - nb0], 1);
        if(pos < BCAP) stage[pos] = e;
        else col[gbase + pos] = e.x;
    }
    __syncthreads();
    int lim = (cnt < BCAP) ? cnt : BCAP;
    for(int i = t; i < lim; i += 512)
        col[gbase + i] = stage[i].x;
}

// ---------------- GEMM: C[N x 64] = A[N x K] * W[K x 64] (+bias) (+score epilogue)
// SCALEA=1: A rows are unnormalized aggregates U; apply h = elu(U * exp(m_n - M) * invZ)
// during the A-load. NOTE: no atomics in the epilogue -- Round-4 showed one atomicMax
// per wave to a single address costs ~60us/dispatch (same-address RMW serialization).
template<int K, int AMODE, bool WITH_BIAS, bool WITH_SCORES, bool CBF16, int SCALEA>
__global__ __launch_bounds__(256) void k_gemm(
    const void* __restrict__ Aptr,
    const void* __restrict__ Wb,   int woff,
    const void* __restrict__ biasb,
    const void* __restrict__ attnb, int aoff,
    const int*  __restrict__ flags,
    void* __restrict__ Cout,
    float* __restrict__ s_src,
    float* __restrict__ s_dst,
    const float2* __restrict__ mzv,
    const float2* __restrict__ MZg)
{
    __shared__ float At[64][68];
    __shared__ float Wf[64][64];
    const bool wf32 = flags[0] != 0;
    const bool af32 = (AMODE == 2) ? true : wf32;
    const int t = threadIdx.x;
    const int block_row = blockIdx.x * 64;
    const int r_load = t >> 2;
    const int q_load = t & 3;
    const int grow_load = block_row + r_load;

    const int c0 = (t & 15) * 4;
    const int r0 = (t >> 4) * 4;

    float sA = 1.f;
    if constexpr (SCALEA == 1){
        float2 gz = MZg[0];
        float2 nm = (grow_load < NODES) ? mzv[grow_load] : make_float2(SENTINEL, 0.f);
        sA = __expf(nm.x - gz.x) * gz.y;
    }

    float acc[4][4] = {{0.f,0.f,0.f,0.f},{0.f,0.f,0.f,0.f},{0.f,0.f,0.f,0.f},{0.f,0.f,0.f,0.f}};

    for(int kb = 0; kb < K; kb += 64){
        if(wf32){
            const float4* wv = (const float4*)Wb;
            for(int v = t; v < 1024; v += 256){
                float4 u = wv[(size_t)(woff + kb*64)/4 + v];
                int f = v*4; int k = f >> 6; int c = f & 63;
                Wf[k][c]=u.x; Wf[k][c+1]=u.y; Wf[k][c+2]=u.z; Wf[k][c+3]=u.w;
            }
        } else {
            const uint4* wv = (const uint4*)Wb;
            for(int v = t; v < 512; v += 256){
                uint4 u = wv[(size_t)(woff + kb*64)/8 + v];
                float o[8]; unpack8(u, o);
                int f = v*8; int k = f >> 6; int c = f & 63;
                #pragma unroll
                for(int j=0;j<8;j++) Wf[k][c+j] = o[j];
            }
        }
        if(af32){
            const float4* av = (const float4*)Aptr;
            #pragma unroll
            for(int i=0;i<4;i++){
                int vi = q_load + 4*i;
                int k0 = vi*4;
                float4 u = make_float4(0.f,0.f,0.f,0.f);
                if(grow_load < NODES) u = av[(size_t)grow_load*(K/4) + (kb>>2) + vi];
                if constexpr (SCALEA == 1){
                    u.x = elu_fast(u.x*sA); u.y = elu_fast(u.y*sA);
                    u.z = elu_fast(u.z*sA); u.w = elu_fast(u.w*sA);
                }
                At[k0+0][r_load]=u.x; At[k0+1][r_load]=u.y;
                At[k0+2][r_load]=u.z; At[k0+3][r_load]=u.w;
            }
        } else {
            const uint4* av = (const uint4*)Aptr;
            #pragma unroll
            for(int i=0;i<2;i++){
                int vi = q_load + 4*i;
                int k0 = vi*8;
                float o[8];
                if(grow_load < NODES){
                    uint4 u = av[(size_t)grow_load*(K/8) + (kb>>3) + vi];
                    unpack8(u, o);
                } else {
                    #pragma unroll
                    for(int j=0;j<8;j++) o[j]=0.f;
                }
                #pragma unroll
                for(int j=0;j<8;j++) At[k0+j][r_load] = o[j];
            }
        }
        __syncthreads();
        #pragma unroll 8
        for(int k=0;k<64;k++){
            float4 a = *(const float4*)&At[k][r0];
            float4 w = *(const float4*)&Wf[k][c0];
            float av4[4] = {a.x,a.y,a.z,a.w};
            float wv4[4] = {w.x,w.y,w.z,w.w};
            #pragma unroll
            for(int i=0;i<4;i++)
                #pragma unroll
                for(int j=0;j<4;j++)
                    acc[i][j] = fmaf(av4[i], wv4[j], acc[i][j]);
        }
        __syncthreads();
    }

    float bias[4] = {0.f,0.f,0.f,0.f};
    if constexpr (WITH_BIAS){
        #pragma unroll
        for(int j=0;j<4;j++) bias[j] = ldin(biasb, c0+j, wf32);
    }
    #pragma unroll
    for(int i=0;i<4;i++){
        int grow = block_row + r0 + i;
        if(grow < NODES){
            if constexpr (CBF16){
                ushort4 o;
                o.x = f2b(acc[i][0]+bias[0]); o.y = f2b(acc[i][1]+bias[1]);
                o.z = f2b(acc[i][2]+bias[2]); o.w = f2b(acc[i][3]+bias[3]);
                *(ushort4*)((unsigned short*)Cout + (size_t)grow*64 + c0) = o;
            } else {
                float4 o = make_float4(acc[i][0]+bias[0], acc[i][1]+bias[1],
                                       acc[i][2]+bias[2], acc[i][3]+bias[3]);
                *(float4*)((float*)Cout + (size_t)grow*64 + c0) = o;
            }
        }
    }
    if constexpr (WITH_SCORES){
        float as[4], ad[4];
        #pragma unroll
        for(int j=0;j<4;j++){
            as[j] = ldin(attnb, aoff + c0+j, wf32);
            ad[j] = ldin(attnb, aoff + 64+c0+j, wf32);
        }
        #pragma unroll
        for(int i=0;i<4;i++){
            float ps = 0.f, pd = 0.f;
            #pragma unroll
            for(int j=0;j<4;j++){ ps = fmaf(acc[i][j], as[j], ps); pd = fmaf(acc[i][j], ad[j], pd); }
            for(int off=1; off<16; off<<=1){
                ps += __shfl_xor(ps, off, 64);
                pd += __shfl_xor(pd, off, 64);
            }
            int grow = block_row + r0 + i;
            if((t & 15) == 0 && grow < NODES){ s_src[grow] = ps; s_dst[grow] = pd; }
        }
    }
}

// ---------------- S* = max over nodes of ssrc: grid-stride, 1 atomic per BLOCK ----
__global__ __launch_bounds__(256) void k_smax(const float* __restrict__ ssrc,
                                              unsigned* __restrict__ smaxk){
    int tid = blockIdx.x*256 + threadIdx.x;
    int stride = gridDim.x*256;
    float m = SENTINEL;
    for(int i = tid; i < NODES; i += stride) m = fmaxf(m, ssrc[i]);
    #pragma unroll
    for(int off=1; off<64; off<<=1) m = fmaxf(m, __shfl_xor(m, off, 64));
    __shared__ float sm[4];
    int w = threadIdx.x >> 6;
    if((threadIdx.x & 63) == 0) sm[w] = m;
    __syncthreads();
    if(threadIdx.x == 0){
        for(int i=1;i<4;i++) m = fmaxf(m, sm[i]);
        atomicMax(smaxk, fenc(m));
    }
}

// ---------------- fused aggregate: 8 NODES PER WAVE (8-lane slice per node).
// Each lane owns 8 features (one uint4 of the bf16 row) -> no cross-lane acc
// reduce at all; the j-loop is branchless (always 8): tail/masked edges have
// w = 0 via exp underflow and their gathers hit row 0 (L1-hot, harmless).
// Gathers are UNGUARDED so the 8 wh16 gathers depend only on the col load and
// overlap the ssrc gather + exp chain -> 8 independent chains per wave.
// Shift m_n = S* + sdst[n] (S* from k_smax) keeps w in (0,1]. Emits unnormalized
// U_n and (m_n, z_n); global normalization exp(m_n - M)/Z applied by consumer.
__global__ __launch_bounds__(256) void k_aggregate(const unsigned short* __restrict__ wh16,
    const int* __restrict__ row_start, const int* __restrict__ col,
    const float* __restrict__ ssrc, const float* __restrict__ sdst,
    const unsigned* __restrict__ smaxk,
    float* __restrict__ U, float2* __restrict__ mz)
{
    int gw = (blockIdx.x*256 + threadIdx.x) >> 3;   // one 8-lane slice per node
    if(gw >= NODES) return;                          // whole slice exits together
    int l8 = threadIdx.x & 7;                        // lane within slice
    int sb = (threadIdx.x & 63) & ~7;                // slice base lane within wave
    int c8 = l8 * 8;                                 // feature slice base
    int beg = row_start[gw], end = row_start[gw+1];
    float sdn = sdst[gw];
    const float m = fdec(*smaxk) + sdn;              // wave-uniform-per-slice bound
    float zl = 0.f;
    float acc[8] = {0.f,0.f,0.f,0.f,0.f,0.f,0.f,0.f};
    for(int base = beg; base < end; base += 8){
        int idx = base + l8;
        bool vld = idx < end;
        int   s_l = vld ? col[idx] : 0;
        float v   = ssrc[s_l] + sdn;                 // hot 400KB gather (overlaps below)
        float att = (vld && v > 0.f) ? v : NEG_BIG_F;
        float w_l = __expf(att - m);                 // (0,1]; exactly 0 invalid/masked
        zl += w_l;
        #pragma unroll
        for(int j = 0; j < 8; j++){
            int   s = __shfl(s_l, sb + j, 64);       // depends only on col load
            float a = __shfl(w_l, sb + j, 64);
            uint4 u = *(const uint4*)&wh16[(size_t)s*64 + c8];   // unguarded
            acc[0] = fmaf(a, bits2f(u.x & 0xffffu), acc[0]);
            acc[1] = fmaf(a, bits2f(u.x >> 16),     acc[1]);
            acc[2] = fmaf(a, bits2f(u.y & 0xffffu), acc[2]);
            acc[3] = fmaf(a, bits2f(u.y >> 16),     acc[3]);
            acc[4] = fmaf(a, bits2f(u.z & 0xffffu), acc[4]);
            acc[5] = fmaf(a, bits2f(u.z >> 16),     acc[5]);
            acc[6] = fmaf(a, bits2f(u.w & 0xffffu), acc[6]);
            acc[7] = fmaf(a, bits2f(u.w >> 16),     acc[7]);
        }
    }
    // z reduce within the 8-lane slice only (xor of bits 0..2 stays in-slice)
    zl += __shfl_xor(zl, 1, 64);
    zl += __shfl_xor(zl, 2, 64);
    zl += __shfl_xor(zl, 4, 64);
    if(l8 == 0) mz[gw] = make_float2(m, zl);
    // each lane owns its 8 features -> direct coalesced store (2KB/wave, contiguous)
    *(float4*)&U[(size_t)gw*64 + c8 + 0] = make_float4(acc[0],acc[1],acc[2],acc[3]);
    *(float4*)&U[(size_t)gw*64 + c8 + 4] = make_float4(acc[4],acc[5],acc[6],acc[7]);
}

// ---------------- node (m,z) -> global (M, 1/Z), two-stage ----------------
__global__ __launch_bounds__(256) void k_mz_part(const float2* __restrict__ mz,
                                                 float2* __restrict__ bmz){
    int tid = blockIdx.x*256 + threadIdx.x;
    int stride = gridDim.x*256;
    float m = SENTINEL, z = 0.f;
    for(int i = tid; i < NODES; i += stride){
        float2 e = mz[i];
        float M = fmaxf(m, e.x);
        z = z*__expf(m - M) + e.y*__expf(e.x - M);
        m = M;
    }
    for(int off=1; off<64; off<<=1){
        float m2 = __shfl_xor(m, off, 64), z2 = __shfl_xor(z, off, 64);
        float M = fmaxf(m, m2);
        z = z*__expf(m - M) + z2*__expf(m2 - M);
        m = M;
    }
    __shared__ float sm[4], sz[4];
    int w = threadIdx.x >> 6;
    if((threadIdx.x & 63) == 0){ sm[w] = m; sz[w] = z; }
    __syncthreads();
    if(threadIdx.x == 0){
        for(int i=1;i<4;i++){
            float M = fmaxf(m, sm[i]);
            z = z*__expf(m - M) + sz[i]*__expf(sm[i] - M);
            m = M;
        }
        bmz[blockIdx.x] = make_float2(m, z);
    }
}

__global__ __launch_bounds__(256) void k_mz_final(const float2* __restrict__ bmz,
                                                  float2* __restrict__ MZ,
                                                  unsigned* __restrict__ smaxk){
    int t = threadIdx.x;
    float m = SENTINEL, z = 0.f;
    for(int i = t; i < MZPB; i += 256){
        float2 e = bmz[i];
        float M = fmaxf(m, e.x);
        z = z*__expf(m - M) + e.y*__expf(e.x - M);
        m = M;
    }
    for(int off=1; off<64; off<<=1){
        float m2 = __shfl_xor(m, off, 64), z2 = __shfl_xor(z, off, 64);
        float M = fmaxf(m, m2);
        z = z*__expf(m - M) + z2*__expf(m2 - M);
        m = M;
    }
    __shared__ float sm[4], sz[4];
    int w = t >> 6;
    if((t & 63) == 0){ sm[w] = m; sz[w] = z; }
    __syncthreads();
    if(t == 0){
        for(int i=1;i<4;i++){
            float M = fmaxf(m, sm[i]);
            z = z*__expf(m - M) + sz[i]*__expf(sm[i] - M);
            m = M;
        }
        MZ[0] = make_float2(m, 1.0f / z);
        smaxk[0] = 0u;   // reset S* accumulator for the next layer
    }
}

// ---------------- fused out-proj + elu + log_softmax, GEMM-tiled (fp32 output).
// Input is unnormalized U2: apply h = elu(U * exp(m_n - M) * invZ) during H-load.
__global__ __launch_bounds__(256) void k_out(const float* __restrict__ h,
    const float2* __restrict__ mzv, const float2* __restrict__ MZg,
    const void* __restrict__ Wo, const void* __restrict__ bo,
    const int* __restrict__ flags, float* __restrict__ out)
{
    __shared__ float Ht[64][65];
    __shared__ float Wsh[64][44];
    __shared__ float logits[64][44];
    __shared__ float rlz[64];
    bool f32 = flags[0] != 0;
    int t = threadIdx.x;
    int block_row = blockIdx.x * 64;

    for(int i = t; i < 64*NCLS; i += 256){
        Wsh[i/NCLS][i%NCLS] = ldin(Wo, i, f32);
    }
    {
        int r_load = t >> 2, q = t & 3;
        int grow = block_row + r_load;
        const float4* hv = (const float4*)h;
        float2 gz = MZg[0];
        float2 nm = (grow < NODES) ? mzv[grow] : make_float2(SENTINEL, 0.f);
        float sA = __expf(nm.x - gz.x) * gz.y;
        #pragma unroll
        for(int i = 0; i < 4; i++){
            int vi = q + 4*i;
            float4 u = make_float4(0.f,0.f,0.f,0.f);
            if(grow < NODES) u = hv[(size_t)grow*16 + vi];
            u.x = elu_fast(u.x*sA); u.y = elu_fast(u.y*sA);
            u.z = elu_fast(u.z*sA); u.w = elu_fast(u.w*sA);
            Ht[vi*4+0][r_load] = u.x; Ht[vi*4+1][r_load] = u.y;
            Ht[vi*4+2][r_load] = u.z; Ht[vi*4+3][r_load] = u.w;
        }
    }
    __syncthreads();

    int cg = t & 15, rg = t >> 4;
    int c0 = cg * 4, r0 = rg * 4;
    if(cg < 10){
        float acc[4][4] = {{0.f,0.f,0.f,0.f},{0.f,0.f,0.f,0.f},{0.f,0.f,0.f,0.f},{0.f,0.f,0.f,0.f}};
        #pragma unroll 8
        for(int k = 0; k < 64; k++){
            float4 a = *(const float4*)&Ht[k][r0];
            float4 w = *(const float4*)&Wsh[k][c0];
            float av4[4] = {a.x,a.y,a.z,a.w};
            float wv4[4] = {w.x,w.y,w.z,w.w};
            #pragma unroll
            for(int i=0;i<4;i++)
                #pragma unroll
                for(int j=0;j<4;j++)
                    acc[i][j] = fmaf(av4[i], wv4[j], acc[i][j]);
        }
        float b[4];
        #pragma unroll
        for(int j=0;j<4;j++) b[j] = ldin(bo, c0+j, f32);
        #pragma unroll
        for(int i=0;i<4;i++)
            #pragma unroll
            for(int j=0;j<4;j++){
                logits[r0+i][c0+j] = elu_fast(acc[i][j] + b[j]);
            }
    }
    __syncthreads();

    {
        int r = t >> 2, qq = t & 3;
        float m = SENTINEL;
        #pragma unroll
        for(int i=0;i<10;i++) m = fmaxf(m, logits[r][qq*10 + i]);
        m = fmaxf(m, __shfl_xor(m, 1, 64));
        m = fmaxf(m, __shfl_xor(m, 2, 64));
        float s = 0.f;
        #pragma unroll
        for(int i=0;i<10;i++) s += __expf(logits[r][qq*10 + i] - m);
        s += __shfl_xor(s, 1, 64);
        s += __shfl_xor(s, 2, 64);
        if(qq == 0) rlz[r] = m + logf(s);
    }
    __syncthreads();

    for(int i = t; i < 64*NCLS; i += 256){
        int rr = i / NCLS, cc = i % NCLS;
        if(block_row + rr < NODES)
            out[(size_t)(block_row)*NCLS + i] = logits[rr][cc] - rlz[rr];
    }
}

extern "C" void kernel_launch(void* const* d_in, const int* in_sizes, int n_in,
                              void* d_out, int out_size, void* d_ws, size_t ws_size,
                              hipStream_t stream)
{
    const void* x      = d_in[0];
    const int*  ei     = (const int*)d_in[1];
    const void* emb_w  = d_in[2];
    const void* emb_b  = d_in[3];
    const void* Ws     = d_in[4];
    const void* attn_a = d_in[5];
    const void* out_w  = d_in[6];
    const void* out_b  = d_in[7];
    float* out = (float*)d_out;

    char* ws = (char*)d_ws;
    size_t off = 0;
    auto alloc = [&](size_t bytes)->char*{
        char* p = ws + off;
        off = (off + bytes + 255) & ~(size_t)255;
        return p;
    };
    int*    flags   = (int*)   alloc(256);
    float*  h       = (float*) alloc((size_t)NODES*HID*4);   // emb out / U1 / U2; aliased as phase-A tmp
    unsigned short* wh16 = (unsigned short*)alloc((size_t)NODES*HID*2);
    float*  ssrc    = (float*) alloc((size_t)NODES*4);
    float*  sdst    = (float*) alloc((size_t)NODES*4);
    int*    rowst   = (int*)   alloc((size_t)(NODES+1)*4);
    int*    col     = (int*)   alloc((size_t)EDGES*4);
    float2* mz      = (float2*)alloc((size_t)NODES*8);
    int*    bdeg    = (int*)   alloc(NBUCK*4);
    int*    bstart  = (int*)   alloc((NBUCK+1)*4);
    int*    bcursor = (int*)   alloc(NBUCK*4);
    float2* bmz     = (float2*)alloc(MZPB*8);
    float2* MZ      = (float2*)alloc(16);
    unsigned* smaxk = (unsigned*)alloc(256);

    int2* tmp = (int2*)h;   // consumed before k_gemm writes h

    k_detect<<<1, 256, 0, stream>>>((const unsigned*)x, (const unsigned*)ei, flags);

    hipMemsetAsync(bdeg, 0, NBUCK*4, stream);
    hipMemsetAsync(smaxk, 0, 4, stream);   // encoded -inf
    k_bhist<<<256, 256, 0, stream>>>(ei, flags, bdeg);
    k_bscan<<<1, 256, 0, stream>>>(bdeg, bstart, bcursor);
    k_bucket_scatter<<<NCHUNK, 256, 0, stream>>>(ei, flags, bcursor, tmp);
    k_bucket_sort<<<NBUCK, 512, 0, stream>>>(tmp, bstart, col, rowst);

    k_gemm<INDIM, 0, true, false, false, 0><<<(NODES+63)/64, 256, 0, stream>>>(
        x, emb_w, 0, emb_b, nullptr, 0, flags, h, nullptr, nullptr, nullptr, nullptr);

    // ---- layer 0 ----
    k_gemm<HID, 2, false, true, true, 0><<<(NODES+63)/64, 256, 0, stream>>>(
        h, Ws, 0, nullptr, attn_a, 0, flags, wh16, ssrc, sdst, nullptr, nullptr);
    k_smax<<<SMB, 256, 0, stream>>>(ssrc, smaxk);
    k_aggregate<<<(NODES*8 + 255)/256, 256, 0, stream>>>(wh16, rowst, col, ssrc, sdst, smaxk, h, mz);
    k_mz_part <<<MZPB, 256, 0, stream>>>(mz, bmz);
    k_mz_final<<<1, 256, 0, stream>>>(bmz, MZ, smaxk);   // also resets smaxk

    // ---- layer 1: A = U1 with deferred normalization + ELU fused into A-load ----
    k_gemm<HID, 2, false, true, true, 1><<<(NODES+63)/64, 256, 0, stream>>>(
        h, Ws, HID*HID, nullptr, attn_a, 2*HID, flags, wh16, ssrc, sdst, mz, MZ);
    k_smax<<<SMB, 256, 0, stream>>>(ssrc, smaxk);
    k_aggregate<<<(NODES*8 + 255)/256, 256, 0, stream>>>(wh16, rowst, col, ssrc, sdst, smaxk, h, mz);
    k_mz_part <<<MZPB, 256, 0, stream>>>(mz, bmz);
    k_mz_final<<<1, 256, 0, stream>>>(bmz, MZ, smaxk);

    k_out<<<(NODES+63)/64, 256, 0, stream>>>(h, mz, MZ, out_w, out_b, flags, out);
}

// Round 7
// 309.993 us; speedup vs baseline: 1.5211x; 1.0736x over previous
//
#include <hip/hip_runtime.h>
#include <hip/hip_bf16.h>

#define NODES   100000
#define EDGES   1600000
#define INDIM   128
#define HID     64
#define NCLS    40
#define NEG_BIG_F (-9000000000000000.0f)
#define SENTINEL  (-3.0e38f)

#define BN       512                 // dst-nodes per coarse bucket (dst >> 9)
#define NBUCK    196                 // ceil(100000/512)
#define CHUNK    7168                // edges per phase-A block
#define NCHUNK   ((EDGES + CHUNK - 1) / CHUNK)   // 224
#define BCAP     8960                // phase-B stage capacity (mean 8192)
#define MZPB     256                 // node-mz partial blocks
#define SMB      128                 // k_smax blocks (1 atomic per block)

using bf16x8 = __attribute__((ext_vector_type(8))) short;  // 8 bf16 (4 VGPRs)
using f32x4  = __attribute__((ext_vector_type(4))) float;  // 4 fp32 acc

static __device__ __forceinline__ float b2f(__hip_bfloat16 h){
    return __bfloat162float(h);
}
static __device__ __forceinline__ float bits2f(unsigned int b){
    union { unsigned int u; float f; } v; v.u = b << 16; return v.f;
}
static __device__ __forceinline__ unsigned short f2b(float f){
    __hip_bfloat16 h = __float2bfloat16(f);
    return *reinterpret_cast<unsigned short*>(&h);
}
static __device__ __forceinline__ float ldin(const void* p, int i, bool f32){
    return f32 ? ((const float*)p)[i] : b2f(((const __hip_bfloat16*)p)[i]);
}
// fast ELU: expm1f is a ~30-instruction libm expansion; __expf(x)-1 is 3 instr.
static __device__ __forceinline__ float elu_fast(float x){
    return (x > 0.f) ? x : (__expf(x) - 1.f);
}
// order-preserving float<->uint encoding for atomicMax on floats
static __device__ __forceinline__ unsigned fenc(float f){
    unsigned u = __float_as_uint(f);
    return (u & 0x80000000u) ? ~u : (u | 0x80000000u);
}
static __device__ __forceinline__ float fdec(unsigned k){
    return __uint_as_float((k & 0x80000000u) ? (k & 0x7fffffffu) : ~k);
}
static __device__ __forceinline__ int ld_src(const int* ei, int i, bool i64){
    return i64 ? ei[2*i] : ei[i];
}
static __device__ __forceinline__ int ld_dst(const int* ei, int i, bool i64){
    return i64 ? ei[2*(EDGES + i)] : ei[EDGES + i];
}

// flags[0]=1 if floats are fp32; flags[1]=1 if edge_index is int64
__global__ __launch_bounds__(256) void k_detect(const unsigned* __restrict__ xw,
                                                const unsigned* __restrict__ eiw,
                                                int* __restrict__ flags){
    __shared__ int s1[256], s2[256];
    int t = threadIdx.x;
    int c1 = 0, c2 = 0;
    for(int i = t; i < 1024; i += 256){
        unsigned e = (xw[i] >> 23) & 0xffu;
        c1 += (e >= 90u && e <= 160u) ? 1 : 0;
        c2 += (eiw[2*i + 1] == 0u) ? 1 : 0;
    }
    s1[t] = c1; s2[t] = c2; __syncthreads();
    for(int off = 128; off > 0; off >>= 1){
        if(t < off){ s1[t] += s1[t+off]; s2[t] += s2[t+off]; }
        __syncthreads();
    }
    if(t == 0){ flags[0] = (s1[0] > 512) ? 1 : 0; flags[1] = (s2[0] > 512) ? 1 : 0; }
}

// ---------------- bucket histogram ----------------
__global__ __launch_bounds__(256) void k_bhist(const int* __restrict__ ei,
                                               const int* __restrict__ flags,
                                               int* __restrict__ bdeg){
    __shared__ int sh[NBUCK];
    bool i64 = flags[1] != 0;
    int t = threadIdx.x;
    for(int i = t; i < NBUCK; i += 256) sh[i] = 0;
    __syncthreads();
    int i = blockIdx.x*256 + t;
    int stride = gridDim.x*256;
    for(; i < EDGES; i += stride) atomicAdd(&sh[ld_dst(ei, i, i64) >> 9], 1);
    __syncthreads();
    for(int b = t; b < NBUCK; b += 256) if(sh[b]) atomicAdd(&bdeg[b], sh[b]);
}

// parallel exclusive scan over NBUCK buckets
__global__ __launch_bounds__(256) void k_bscan(const int* __restrict__ bdeg,
                        int* __restrict__ bstart, int* __restrict__ bcursor){
    __shared__ int sh[256];
    int t = threadIdx.x;
    int v = (t < NBUCK) ? bdeg[t] : 0;
    sh[t] = v; __syncthreads();
    for(int off = 1; off < 256; off <<= 1){
        int x = (t >= off) ? sh[t - off] : 0;
        __syncthreads();
        sh[t] += x;
        __syncthreads();
    }
    int excl = sh[t] - v;
    if(t < NBUCK){ bstart[t] = excl; bcursor[t] = excl; }
    if(t == 255) bstart[NBUCK] = sh[255];
}

// ---------------- phase A: LDS-binned coarse scatter ----------------
__global__ __launch_bounds__(256) void k_bucket_scatter(const int* __restrict__ ei,
    const int* __restrict__ flags, int* __restrict__ bcursor, int2* __restrict__ tmp){
    __shared__ int  sCnt[NBUCK], sScan[NBUCK], sCur[NBUCK], sGofs[NBUCK];
    __shared__ int2 stage[CHUNK];
    bool i64 = flags[1] != 0;
    int t = threadIdx.x;
    int base = blockIdx.x * CHUNK;
    int n = EDGES - base; if(n > CHUNK) n = CHUNK; if(n <= 0) return;

    for(int b = t; b < NBUCK; b += 256) sCnt[b] = 0;
    __syncthreads();
    for(int j = t; j < n; j += 256)
        atomicAdd(&sCnt[ld_dst(ei, base + j, i64) >> 9], 1);
    __syncthreads();
    for(int b = t; b < NBUCK; b += 256) sScan[b] = sCnt[b];
    __syncthreads();
    for(int off = 1; off < NBUCK; off <<= 1){
        int v = 0;
        if(t < NBUCK && t >= off) v = sScan[t - off];
        __syncthreads();
        if(t < NBUCK) sScan[t] += v;
        __syncthreads();
    }
    if(t < NBUCK){
        int excl = sScan[t] - sCnt[t];
        sCur[t]  = excl;
        sGofs[t] = sCnt[t] ? atomicAdd(&bcursor[t], sCnt[t]) : 0;
    }
    __syncthreads();
    for(int j = t; j < n; j += 256){
        int src = ld_src(ei, base + j, i64);
        int dst = ld_dst(ei, base + j, i64);
        int pos = atomicAdd(&sCur[dst >> 9], 1);
        stage[pos] = make_int2(src, dst);
    }
    __syncthreads();
    for(int i = t; i < n; i += 256){
        int2 e = stage[i];
        int  b = e.y >> 9;
        int  excl = sScan[b] - sCnt[b];
        tmp[(size_t)sGofs[b] + (i - excl)] = e;
    }
}

// ---------------- phase B: per-bucket counting sort -> col + rowst ----------------
__global__ __launch_bounds__(512) void k_bucket_sort(const int2* __restrict__ tmp,
    const int* __restrict__ bstart, int* __restrict__ col,
    int* __restrict__ rowst){
    __shared__ int  sCnt[BN], sScan[BN], sCur[BN];
    __shared__ int2 stage[BCAP];
    int b = blockIdx.x, t = threadIdx.x;
    int nb0 = b * BN;
    int gbase = bstart[b], gend = bstart[b+1];
    int cnt = gend - gbase;

    if(t < BN) sCnt[t] = 0;
    __syncthreads();
    for(int j = gbase + t; j < gend; j += 512)
        atomicAdd(&sCnt[tmp[j].y - nb0], 1);
    __syncthreads();
    if(t < BN) sScan[t] = sCnt[t];
    __syncthreads();
    for(int off = 1; off < BN; off <<= 1){
        int v = 0;
        if(t < BN && t >= off) v = sScan[t - off];
        __syncthreads();
        if(t < BN) sScan[t] += v;
        __syncthreads();
    }
    if(t < BN) sCur[t] = sScan[t] - sCnt[t];
    if(t < BN && (nb0 + t) < NODES) rowst[nb0 + t] = gbase + (sScan[t] - sCnt[t]);
    if(b == 0 && t == 0) rowst[NODES] = EDGES;
    __syncthreads();
    for(int j = gbase + t; j < gend; j += 512){
        int2 e = tmp[j];
        int pos = atomicAdd(&sCur[e.y - nb0], 1);
        if(pos < BCAP) stage[pos] = e;
        else col[gbase + pos] = e.x;
    }
    __syncthreads();
    int lim = (cnt < BCAP) ? cnt : BCAP;
    for(int i = t; i < lim; i += 512)
        col[gbase + i] = stage[i].x;
}

// ---------------- MFMA GEMM: C[N x 64] = A[N x K] * W[K x 64] (+bias) (+scores)
// 64x64 tile, 4 waves, wave w owns rows 16w..16w+15; v_mfma_f32_16x16x32_bf16.
// Fragment layouts (HW-verified, cdna4 guide S3): A row=l&15, k=8*(l>>4)+e;
// B col=l&15, same k; D col=l&15, row=(l>>4)*4+reg.
// A staged bf16 [64][72] row-major (stride 72 shorts = 144 B keeps ds_read_b128
// 16B-aligned); W staged TRANSPOSED Bs[col][k] so B-frag is one contiguous b128.
// SCALEA=1: A rows are unnormalized aggregates U; h = elu(U * exp(m_n-M) * invZ)
// applied during staging. No atomics anywhere (Round-4 lesson).
template<int K, int AMODE, bool WITH_BIAS, bool WITH_SCORES, bool CBF16, int SCALEA>
__global__ __launch_bounds__(256) void k_gemm(
    const void* __restrict__ Aptr,
    const void* __restrict__ Wb,   int woff,
    const void* __restrict__ biasb,
    const void* __restrict__ attnb, int aoff,
    const int*  __restrict__ flags,
    void* __restrict__ Cout,
    float* __restrict__ s_src,
    float* __restrict__ s_dst,
    const float2* __restrict__ mzv,
    const float2* __restrict__ MZg)
{
    __shared__ short As[64][72];   // A tile bf16, rows x k-chunk
    __shared__ short Bs[64][72];   // W tile bf16 TRANSPOSED: [col][k-chunk]
    const bool wf32 = flags[0] != 0;
    const bool af32 = (AMODE == 2) ? true : wf32;
    const int t = threadIdx.x;
    const int block_row = blockIdx.x * 64;
    const int w  = t >> 6;           // wave id: rows 16w..16w+15
    const int l  = t & 63;
    const int srow = t >> 2;         // staging row 0..63
    const int sq   = t & 3;          // staging quarter (16 k's)
    const int grow_s = block_row + srow;

    float sA = 1.f;
    if constexpr (SCALEA == 1){
        float2 gz = MZg[0];
        float2 nm = (grow_s < NODES) ? mzv[grow_s] : make_float2(SENTINEL, 0.f);
        sA = __expf(nm.x - gz.x) * gz.y;
    }

    f32x4 acc[4] = { {0.f,0.f,0.f,0.f},{0.f,0.f,0.f,0.f},
                     {0.f,0.f,0.f,0.f},{0.f,0.f,0.f,0.f} };

    for(int kb = 0; kb < K; kb += 64){
        // ---- stage A chunk: As[row][k] = bf16(A[grow_s][kb+k]), k = sq*16..+15 ----
        {
            unsigned o[16];
            if(af32){
                const float4* av4 = (const float4*)((const float*)Aptr + (size_t)grow_s*K + kb);
                #pragma unroll
                for(int i=0;i<4;i++){
                    float4 u = make_float4(0.f,0.f,0.f,0.f);
                    if(grow_s < NODES) u = av4[sq*4 + i];
                    if constexpr (SCALEA == 1){
                        u.x = elu_fast(u.x*sA); u.y = elu_fast(u.y*sA);
                        u.z = elu_fast(u.z*sA); u.w = elu_fast(u.w*sA);
                    }
                    o[4*i+0]=f2b(u.x); o[4*i+1]=f2b(u.y);
                    o[4*i+2]=f2b(u.z); o[4*i+3]=f2b(u.w);
                }
            } else {
                const uint4* avb = (const uint4*)((const unsigned short*)Aptr + (size_t)grow_s*K + kb);
                #pragma unroll
                for(int i=0;i<2;i++){
                    uint4 u = make_uint4(0,0,0,0);
                    if(grow_s < NODES) u = avb[sq*2 + i];
                    o[8*i+0]=u.x&0xffffu; o[8*i+1]=u.x>>16;
                    o[8*i+2]=u.y&0xffffu; o[8*i+3]=u.y>>16;
                    o[8*i+4]=u.z&0xffffu; o[8*i+5]=u.z>>16;
                    o[8*i+6]=u.w&0xffffu; o[8*i+7]=u.w>>16;
                }
            }
            uint4* dst = (uint4*)&As[srow][sq*16];   // 144B row stride: 16B aligned
            dst[0] = make_uint4(o[0]|(o[1]<<16),  o[2]|(o[3]<<16),
                                o[4]|(o[5]<<16),  o[6]|(o[7]<<16));
            dst[1] = make_uint4(o[8]|(o[9]<<16),  o[10]|(o[11]<<16),
                                o[12]|(o[13]<<16),o[14]|(o[15]<<16));
        }
        // ---- stage W chunk transposed: Bs[col][k] (coalesced global reads) ----
        if(wf32){
            const float* wv = (const float*)Wb + woff + (size_t)kb*64;
            #pragma unroll
            for(int i=0;i<16;i++){
                int idx = t + 256*i;               // 0..4095 = k*64 + col
                Bs[idx & 63][idx >> 6] = (short)f2b(wv[idx]);
            }
        } else {
            const unsigned short* wv = (const unsigned short*)Wb + woff + (size_t)kb*64;
            #pragma unroll
            for(int i=0;i<16;i++){
                int idx = t + 256*i;
                Bs[idx & 63][idx >> 6] = (short)wv[idx];
            }
        }
        __syncthreads();
        // ---- MFMA: wave w rows, 4 col-subtiles, 2 K-steps of 32 ----
        #pragma unroll
        for(int s=0;s<2;s++){
            int k0 = s*32 + 8*(l >> 4);
            bf16x8 a = *(const bf16x8*)&As[16*w + (l & 15)][k0];
            #pragma unroll
            for(int c=0;c<4;c++){
                bf16x8 b = *(const bf16x8*)&Bs[16*c + (l & 15)][k0];
                acc[c] = __builtin_amdgcn_mfma_f32_16x16x32_bf16(a, b, acc[c], 0, 0, 0);
            }
        }
        __syncthreads();
    }

    // ---- epilogue: D col = l&15 (within subtile), row = (l>>4)*4 + r ----
    const int lg4 = (l >> 4) * 4;
    const int lc  = l & 15;
    float bias[4] = {0.f,0.f,0.f,0.f};
    if constexpr (WITH_BIAS){
        #pragma unroll
        for(int c=0;c<4;c++) bias[c] = ldin(biasb, 16*c + lc, wf32);
    }
    #pragma unroll
    for(int r=0;r<4;r++){
        int grow = block_row + 16*w + lg4 + r;
        if(grow < NODES){
            #pragma unroll
            for(int c=0;c<4;c++){
                float vv = acc[c][r] + bias[c];
                if constexpr (CBF16)
                    ((unsigned short*)Cout)[(size_t)grow*64 + 16*c + lc] = f2b(vv);
                else
                    ((float*)Cout)[(size_t)grow*64 + 16*c + lc] = vv;
            }
        }
    }
    if constexpr (WITH_SCORES){
        float as_[4], ad_[4];
        #pragma unroll
        for(int c=0;c<4;c++){
            as_[c] = ldin(attnb, aoff + 16*c + lc, wf32);
            ad_[c] = ldin(attnb, aoff + 64 + 16*c + lc, wf32);
        }
        #pragma unroll
        for(int r=0;r<4;r++){
            float ps = 0.f, pd = 0.f;
            #pragma unroll
            for(int c=0;c<4;c++){
                ps = fmaf(acc[c][r], as_[c], ps);
                pd = fmaf(acc[c][r], ad_[c], pd);
            }
            // reduce across the 16-lane col group (bits 0..3 of lane)
            ps += __shfl_xor(ps, 1, 64); pd += __shfl_xor(pd, 1, 64);
            ps += __shfl_xor(ps, 2, 64); pd += __shfl_xor(pd, 2, 64);
            ps += __shfl_xor(ps, 4, 64); pd += __shfl_xor(pd, 4, 64);
            ps += __shfl_xor(ps, 8, 64); pd += __shfl_xor(pd, 8, 64);
            int grow = block_row + 16*w + lg4 + r;
            if(lc == 0 && grow < NODES){ s_src[grow] = ps; s_dst[grow] = pd; }
        }
    }
}

// ---------------- S* = max over nodes of ssrc: grid-stride, 1 atomic per BLOCK ----
__global__ __launch_bounds__(256) void k_smax(const float* __restrict__ ssrc,
                                              unsigned* __restrict__ smaxk){
    int tid = blockIdx.x*256 + threadIdx.x;
    int stride = gridDim.x*256;
    float m = SENTINEL;
    for(int i = tid; i < NODES; i += stride) m = fmaxf(m, ssrc[i]);
    #pragma unroll
    for(int off=1; off<64; off<<=1) m = fmaxf(m, __shfl_xor(m, off, 64));
    __shared__ float sm[4];
    int w = threadIdx.x >> 6;
    if((threadIdx.x & 63) == 0) sm[w] = m;
    __syncthreads();
    if(threadIdx.x == 0){
        for(int i=1;i<4;i++) m = fmaxf(m, sm[i]);
        atomicMax(smaxk, fenc(m));
    }
}

// ---------------- fused aggregate: 8 NODES PER WAVE (8-lane slice per node).
// Branchless 8-edge inner loop; unguarded gathers overlap the ssrc gather + exp.
// Shift m_n = S* + sdst[n]; emits unnormalized U_n and (m_n, z_n).
__global__ __launch_bounds__(256) void k_aggregate(const unsigned short* __restrict__ wh16,
    const int* __restrict__ row_start, const int* __restrict__ col,
    const float* __restrict__ ssrc, const float* __restrict__ sdst,
    const unsigned* __restrict__ smaxk,
    float* __restrict__ U, float2* __restrict__ mz)
{
    int gw = (blockIdx.x*256 + threadIdx.x) >> 3;   // one 8-lane slice per node
    if(gw >= NODES) return;
    int l8 = threadIdx.x & 7;
    int sb = (threadIdx.x & 63) & ~7;
    int c8 = l8 * 8;
    int beg = row_start[gw], end = row_start[gw+1];
    float sdn = sdst[gw];
    const float m = fdec(*smaxk) + sdn;
    float zl = 0.f;
    float acc[8] = {0.f,0.f,0.f,0.f,0.f,0.f,0.f,0.f};
    for(int base = beg; base < end; base += 8){
        int idx = base + l8;
        bool vld = idx < end;
        int   s_l = vld ? col[idx] : 0;
        float v   = ssrc[s_l] + sdn;
        float att = (vld && v > 0.f) ? v : NEG_BIG_F;
        float w_l = __expf(att - m);
        zl += w_l;
        #pragma unroll
        for(int j = 0; j < 8; j++){
            int   s = __shfl(s_l, sb + j, 64);
            float a = __shfl(w_l, sb + j, 64);
            uint4 u = *(const uint4*)&wh16[(size_t)s*64 + c8];
            acc[0] = fmaf(a, bits2f(u.x & 0xffffu), acc[0]);
            acc[1] = fmaf(a, bits2f(u.x >> 16),     acc[1]);
            acc[2] = fmaf(a, bits2f(u.y & 0xffffu), acc[2]);
            acc[3] = fmaf(a, bits2f(u.y >> 16),     acc[3]);
            acc[4] = fmaf(a, bits2f(u.z & 0xffffu), acc[4]);
            acc[5] = fmaf(a, bits2f(u.z >> 16),     acc[5]);
            acc[6] = fmaf(a, bits2f(u.w & 0xffffu), acc[6]);
            acc[7] = fmaf(a, bits2f(u.w >> 16),     acc[7]);
        }
    }
    zl += __shfl_xor(zl, 1, 64);
    zl += __shfl_xor(zl, 2, 64);
    zl += __shfl_xor(zl, 4, 64);
    if(l8 == 0) mz[gw] = make_float2(m, zl);
    *(float4*)&U[(size_t)gw*64 + c8 + 0] = make_float4(acc[0],acc[1],acc[2],acc[3]);
    *(float4*)&U[(size_t)gw*64 + c8 + 4] = make_float4(acc[4],acc[5],acc[6],acc[7]);
}

// ---------------- node (m,z) -> global (M, 1/Z), two-stage ----------------
__global__ __launch_bounds__(256) void k_mz_part(const float2* __restrict__ mz,
                                                 float2* __restrict__ bmz){
    int tid = blockIdx.x*256 + threadIdx.x;
    int stride = gridDim.x*256;
    float m = SENTINEL, z = 0.f;
    for(int i = tid; i < NODES; i += stride){
        float2 e = mz[i];
        float M = fmaxf(m, e.x);
        z = z*__expf(m - M) + e.y*__expf(e.x - M);
        m = M;
    }
    for(int off=1; off<64; off<<=1){
        float m2 = __shfl_xor(m, off, 64), z2 = __shfl_xor(z, off, 64);
        float M = fmaxf(m, m2);
        z = z*__expf(m - M) + z2*__expf(m2 - M);
        m = M;
    }
    __shared__ float sm[4], sz[4];
    int w = threadIdx.x >> 6;
    if((threadIdx.x & 63) == 0){ sm[w] = m; sz[w] = z; }
    __syncthreads();
    if(threadIdx.x == 0){
        for(int i=1;i<4;i++){
            float M = fmaxf(m, sm[i]);
            z = z*__expf(m - M) + sz[i]*__expf(sm[i] - M);
            m = M;
        }
        bmz[blockIdx.x] = make_float2(m, z);
    }
}

__global__ __launch_bounds__(256) void k_mz_final(const float2* __restrict__ bmz,
                                                  float2* __restrict__ MZ,
                                                  unsigned* __restrict__ smaxk){
    int t = threadIdx.x;
    float m = SENTINEL, z = 0.f;
    for(int i = t; i < MZPB; i += 256){
        float2 e = bmz[i];
        float M = fmaxf(m, e.x);
        z = z*__expf(m - M) + e.y*__expf(e.x - M);
        m = M;
    }
    for(int off=1; off<64; off<<=1){
        float m2 = __shfl_xor(m, off, 64), z2 = __shfl_xor(z, off, 64);
        float M = fmaxf(m, m2);
        z = z*__expf(m - M) + z2*__expf(m2 - M);
        m = M;
    }
    __shared__ float sm[4], sz[4];
    int w = t >> 6;
    if((t & 63) == 0){ sm[w] = m; sz[w] = z; }
    __syncthreads();
    if(t == 0){
        for(int i=1;i<4;i++){
            float M = fmaxf(m, sm[i]);
            z = z*__expf(m - M) + sz[i]*__expf(sm[i] - M);
            m = M;
        }
        MZ[0] = make_float2(m, 1.0f / z);
        smaxk[0] = 0u;   // reset S* accumulator for the next layer
    }
}

// ---------------- fused out-proj + elu + log_softmax, GEMM-tiled (fp32 output).
// Input is unnormalized U2: apply h = elu(U * exp(m_n - M) * invZ) during H-load.
__global__ __launch_bounds__(256) void k_out(const float* __restrict__ h,
    const float2* __restrict__ mzv, const float2* __restrict__ MZg,
    const void* __restrict__ Wo, const void* __restrict__ bo,
    const int* __restrict__ flags, float* __restrict__ out)
{
    __shared__ float Ht[64][65];
    __shared__ float Wsh[64][44];
    __shared__ float logits[64][44];
    __shared__ float rlz[64];
    bool f32 = flags[0] != 0;
    int t = threadIdx.x;
    int block_row = blockIdx.x * 64;

    for(int i = t; i < 64*NCLS; i += 256){
        Wsh[i/NCLS][i%NCLS] = ldin(Wo, i, f32);
    }
    {
        int r_load = t >> 2, q = t & 3;
        int grow = block_row + r_load;
        const float4* hv = (const float4*)h;
        float2 gz = MZg[0];
        float2 nm = (grow < NODES) ? mzv[grow] : make_float2(SENTINEL, 0.f);
        float sA = __expf(nm.x - gz.x) * gz.y;
        #pragma unroll
        for(int i = 0; i < 4; i++){
            int vi = q + 4*i;
            float4 u = make_float4(0.f,0.f,0.f,0.f);
            if(grow < NODES) u = hv[(size_t)grow*16 + vi];
            u.x = elu_fast(u.x*sA); u.y = elu_fast(u.y*sA);
            u.z = elu_fast(u.z*sA); u.w = elu_fast(u.w*sA);
            Ht[vi*4+0][r_load] = u.x; Ht[vi*4+1][r_load] = u.y;
            Ht[vi*4+2][r_load] = u.z; Ht[vi*4+3][r_load] = u.w;
        }
    }
    __syncthreads();

    int cg = t & 15, rg = t >> 4;
    int c0 = cg * 4, r0 = rg * 4;
    if(cg < 10){
        float acc[4][4] = {{0.f,0.f,0.f,0.f},{0.f,0.f,0.f,0.f},{0.f,0.f,0.f,0.f},{0.f,0.f,0.f,0.f}};
        #pragma unroll 8
        for(int k = 0; k < 64; k++){
            float4 a = *(const float4*)&Ht[k][r0];
            float4 w = *(const float4*)&Wsh[k][c0];
            float av4[4] = {a.x,a.y,a.z,a.w};
            float wv4[4] = {w.x,w.y,w.z,w.w};
            #pragma unroll
            for(int i=0;i<4;i++)
                #pragma unroll
                for(int j=0;j<4;j++)
                    acc[i][j] = fmaf(av4[i], wv4[j], acc[i][j]);
        }
        float b[4];
        #pragma unroll
        for(int j=0;j<4;j++) b[j] = ldin(bo, c0+j, f32);
        #pragma unroll
        for(int i=0;i<4;i++)
            #pragma unroll
            for(int j=0;j<4;j++){
                logits[r0+i][c0+j] = elu_fast(acc[i][j] + b[j]);
            }
    }
    __syncthreads();

    {
        int r = t >> 2, qq = t & 3;
        float m = SENTINEL;
        #pragma unroll
        for(int i=0;i<10;i++) m = fmaxf(m, logits[r][qq*10 + i]);
        m = fmaxf(m, __shfl_xor(m, 1, 64));
        m = fmaxf(m, __shfl_xor(m, 2, 64));
        float s = 0.f;
        #pragma unroll
        for(int i=0;i<10;i++) s += __expf(logits[r][qq*10 + i] - m);
        s += __shfl_xor(s, 1, 64);
        s += __shfl_xor(s, 2, 64);
        if(qq == 0) rlz[r] = m + logf(s);
    }
    __syncthreads();

    for(int i = t; i < 64*NCLS; i += 256){
        int rr = i / NCLS, cc = i % NCLS;
        if(block_row + rr < NODES)
            out[(size_t)(block_row)*NCLS + i] = logits[rr][cc] - rlz[rr];
    }
}

extern "C" void kernel_launch(void* const* d_in, const int* in_sizes, int n_in,
                              void* d_out, int out_size, void* d_ws, size_t ws_size,
                              hipStream_t stream)
{
    const void* x      = d_in[0];
    const int*  ei     = (const int*)d_in[1];
    const void* emb_w  = d_in[2];
    const void* emb_b  = d_in[3];
    const void* Ws     = d_in[4];
    const void* attn_a = d_in[5];
    const void* out_w  = d_in[6];
    const void* out_b  = d_in[7];
    float* out = (float*)d_out;

    char* ws = (char*)d_ws;
    size_t off = 0;
    auto alloc = [&](size_t bytes)->char*{
        char* p = ws + off;
        off = (off + bytes + 255) & ~(size_t)255;
        return p;
    };
    int*    flags   = (int*)   alloc(256);
    float*  h       = (float*) alloc((size_t)NODES*HID*4);   // emb out / U1 / U2; aliased as phase-A tmp
    unsigned short* wh16 = (unsigned short*)alloc((size_t)NODES*HID*2);
    float*  ssrc    = (float*) alloc((size_t)NODES*4);
    float*  sdst    = (float*) alloc((size_t)NODES*4);
    int*    rowst   = (int*)   alloc((size_t)(NODES+1)*4);
    int*    col     = (int*)   alloc((size_t)EDGES*4);
    float2* mz      = (float2*)alloc((size_t)NODES*8);
    int*    bdeg    = (int*)   alloc(NBUCK*4);
    int*    bstart  = (int*)   alloc((NBUCK+1)*4);
    int*    bcursor = (int*)   alloc(NBUCK*4);
    float2* bmz     = (float2*)alloc(MZPB*8);
    float2* MZ      = (float2*)alloc(16);
    unsigned* smaxk = (unsigned*)alloc(256);

    int2* tmp = (int2*)h;   // consumed before k_gemm writes h

    k_detect<<<1, 256, 0, stream>>>((const unsigned*)x, (const unsigned*)ei, flags);

    hipMemsetAsync(bdeg, 0, NBUCK*4, stream);
    hipMemsetAsync(smaxk, 0, 4, stream);   // encoded -inf
    k_bhist<<<256, 256, 0, stream>>>(ei, flags, bdeg);
    k_bscan<<<1, 256, 0, stream>>>(bdeg, bstart, bcursor);
    k_bucket_scatter<<<NCHUNK, 256, 0, stream>>>(ei, flags, bcursor, tmp);
    k_bucket_sort<<<NBUCK, 512, 0, stream>>>(tmp, bstart, col, rowst);

    k_gemm<INDIM, 0, true, false, false, 0><<<(NODES+63)/64, 256, 0, stream>>>(
        x, emb_w, 0, emb_b, nullptr, 0, flags, h, nullptr, nullptr, nullptr, nullptr);

    // ---- layer 0 ----
    k_gemm<HID, 2, false, true, true, 0><<<(NODES+63)/64, 256, 0, stream>>>(
        h, Ws, 0, nullptr, attn_a, 0, flags, wh16, ssrc, sdst, nullptr, nullptr);
    k_smax<<<SMB, 256, 0, stream>>>(ssrc, smaxk);
    k_aggregate<<<(NODES*8 + 255)/256, 256, 0, stream>>>(wh16, rowst, col, ssrc, sdst, smaxk, h, mz);
    k_mz_part <<<MZPB, 256, 0, stream>>>(mz, bmz);
    k_mz_final<<<1, 256, 0, stream>>>(bmz, MZ, smaxk);   // also resets smaxk

    // ---- layer 1: A = U1 with deferred normalization + ELU fused into A-load ----
    k_gemm<HID, 2, false, true, true, 1><<<(NODES+63)/64, 256, 0, stream>>>(
        h, Ws, HID*HID, nullptr, attn_a, 2*HID, flags, wh16, ssrc, sdst, mz, MZ);
    k_smax<<<SMB, 256, 0, stream>>>(ssrc, smaxk);
    k_aggregate<<<(NODES*8 + 255)/256, 256, 0, stream>>>(wh16, rowst, col, ssrc, sdst, smaxk, h, mz);
    k_mz_part <<<MZPB, 256, 0, stream>>>(mz, bmz);
    k_mz_final<<<1, 256, 0, stream>>>(bmz, MZ, smaxk);

    k_out<<<(NODES+63)/64, 256, 0, stream>>>(h, mz, MZ, out_w, out_b, flags, out);
}

// Round 8
// 306.552 us; speedup vs baseline: 1.5382x; 1.0112x over previous
//
#include <hip/hip_runtime.h>
#include <hip/hip_bf16.h>

#define NODES   100000
#define EDGES   1600000
#define INDIM   128
#define HID     64
#define NCLS    40
#define NEG_BIG_F (-9000000000000000.0f)
#define SENTINEL  (-3.0e38f)

#define BN       512                 // dst-nodes per coarse bucket (dst >> 9)
#define NBUCK    196                 // ceil(100000/512)
#define CHUNK    7168                // edges per phase-A block
#define NCHUNK   ((EDGES + CHUNK - 1) / CHUNK)   // 224
#define BCAP     8960                // phase-B stage capacity (mean 8192)
#define MZPB     256                 // node-mz partial blocks
#define SMB      128                 // k_smax blocks (1 atomic per block)

using bf16x8 = __attribute__((ext_vector_type(8))) short;  // 8 bf16 (4 VGPRs)
using f32x4  = __attribute__((ext_vector_type(4))) float;  // 4 fp32 acc

static __device__ __forceinline__ float b2f(__hip_bfloat16 h){
    return __bfloat162float(h);
}
static __device__ __forceinline__ float bits2f(unsigned int b){
    union { unsigned int u; float f; } v; v.u = b << 16; return v.f;
}
static __device__ __forceinline__ unsigned short f2b(float f){
    __hip_bfloat16 h = __float2bfloat16(f);
    return *reinterpret_cast<unsigned short*>(&h);
}
static __device__ __forceinline__ float ldin(const void* p, int i, bool f32){
    return f32 ? ((const float*)p)[i] : b2f(((const __hip_bfloat16*)p)[i]);
}
// fast ELU: expm1f is a ~30-instruction libm expansion; __expf(x)-1 is 3 instr.
static __device__ __forceinline__ float elu_fast(float x){
    return (x > 0.f) ? x : (__expf(x) - 1.f);
}
// order-preserving float<->uint encoding for atomicMax on floats
static __device__ __forceinline__ unsigned fenc(float f){
    unsigned u = __float_as_uint(f);
    return (u & 0x80000000u) ? ~u : (u | 0x80000000u);
}
static __device__ __forceinline__ float fdec(unsigned k){
    return __uint_as_float((k & 0x80000000u) ? (k & 0x7fffffffu) : ~k);
}
static __device__ __forceinline__ int ld_src(const int* ei, int i, bool i64){
    return i64 ? ei[2*i] : ei[i];
}
static __device__ __forceinline__ int ld_dst(const int* ei, int i, bool i64){
    return i64 ? ei[2*(EDGES + i)] : ei[EDGES + i];
}

// flags[0]=1 if floats are fp32; flags[1]=1 if edge_index is int64
__global__ __launch_bounds__(256) void k_detect(const unsigned* __restrict__ xw,
                                                const unsigned* __restrict__ eiw,
                                                int* __restrict__ flags){
    __shared__ int s1[256], s2[256];
    int t = threadIdx.x;
    int c1 = 0, c2 = 0;
    for(int i = t; i < 1024; i += 256){
        unsigned e = (xw[i] >> 23) & 0xffu;
        c1 += (e >= 90u && e <= 160u) ? 1 : 0;
        c2 += (eiw[2*i + 1] == 0u) ? 1 : 0;
    }
    s1[t] = c1; s2[t] = c2; __syncthreads();
    for(int off = 128; off > 0; off >>= 1){
        if(t < off){ s1[t] += s1[t+off]; s2[t] += s2[t+off]; }
        __syncthreads();
    }
    if(t == 0){ flags[0] = (s1[0] > 512) ? 1 : 0; flags[1] = (s2[0] > 512) ? 1 : 0; }
}

// ---------------- bucket histogram ----------------
__global__ __launch_bounds__(256) void k_bhist(const int* __restrict__ ei,
                                               const int* __restrict__ flags,
                                               int* __restrict__ bdeg){
    __shared__ int sh[NBUCK];
    bool i64 = flags[1] != 0;
    int t = threadIdx.x;
    for(int i = t; i < NBUCK; i += 256) sh[i] = 0;
    __syncthreads();
    int i = blockIdx.x*256 + t;
    int stride = gridDim.x*256;
    for(; i < EDGES; i += stride) atomicAdd(&sh[ld_dst(ei, i, i64) >> 9], 1);
    __syncthreads();
    for(int b = t; b < NBUCK; b += 256) if(sh[b]) atomicAdd(&bdeg[b], sh[b]);
}

// parallel exclusive scan over NBUCK buckets
__global__ __launch_bounds__(256) void k_bscan(const int* __restrict__ bdeg,
                        int* __restrict__ bstart, int* __restrict__ bcursor){
    __shared__ int sh[256];
    int t = threadIdx.x;
    int v = (t < NBUCK) ? bdeg[t] : 0;
    sh[t] = v; __syncthreads();
    for(int off = 1; off < 256; off <<= 1){
        int x = (t >= off) ? sh[t - off] : 0;
        __syncthreads();
        sh[t] += x;
        __syncthreads();
    }
    int excl = sh[t] - v;
    if(t < NBUCK){ bstart[t] = excl; bcursor[t] = excl; }
    if(t == 255) bstart[NBUCK] = sh[255];
}

// ---------------- phase A: LDS-binned coarse scatter ----------------
__global__ __launch_bounds__(256) void k_bucket_scatter(const int* __restrict__ ei,
    const int* __restrict__ flags, int* __restrict__ bcursor, int2* __restrict__ tmp){
    __shared__ int  sCnt[NBUCK], sScan[NBUCK], sCur[NBUCK], sGofs[NBUCK];
    __shared__ int2 stage[CHUNK];
    bool i64 = flags[1] != 0;
    int t = threadIdx.x;
    int base = blockIdx.x * CHUNK;
    int n = EDGES - base; if(n > CHUNK) n = CHUNK; if(n <= 0) return;

    for(int b = t; b < NBUCK; b += 256) sCnt[b] = 0;
    __syncthreads();
    for(int j = t; j < n; j += 256)
        atomicAdd(&sCnt[ld_dst(ei, base + j, i64) >> 9], 1);
    __syncthreads();
    for(int b = t; b < NBUCK; b += 256) sScan[b] = sCnt[b];
    __syncthreads();
    for(int off = 1; off < NBUCK; off <<= 1){
        int v = 0;
        if(t < NBUCK && t >= off) v = sScan[t - off];
        __syncthreads();
        if(t < NBUCK) sScan[t] += v;
        __syncthreads();
    }
    if(t < NBUCK){
        int excl = sScan[t] - sCnt[t];
        sCur[t]  = excl;
        sGofs[t] = sCnt[t] ? atomicAdd(&bcursor[t], sCnt[t]) : 0;
    }
    __syncthreads();
    for(int j = t; j < n; j += 256){
        int src = ld_src(ei, base + j, i64);
        int dst = ld_dst(ei, base + j, i64);
        int pos = atomicAdd(&sCur[dst >> 9], 1);
        stage[pos] = make_int2(src, dst);
    }
    __syncthreads();
    for(int i = t; i < n; i += 256){
        int2 e = stage[i];
        int  b = e.y >> 9;
        int  excl = sScan[b] - sCnt[b];
        tmp[(size_t)sGofs[b] + (i - excl)] = e;
    }
}

// ---------------- phase B: per-bucket counting sort -> col + rowst ----------------
__global__ __launch_bounds__(512) void k_bucket_sort(const int2* __restrict__ tmp,
    const int* __restrict__ bstart, int* __restrict__ col,
    int* __restrict__ rowst){
    __shared__ int  sCnt[BN], sScan[BN], sCur[BN];
    __shared__ int2 stage[BCAP];
    int b = blockIdx.x, t = threadIdx.x;
    int nb0 = b * BN;
    int gbase = bstart[b], gend = bstart[b+1];
    int cnt = gend - gbase;

    if(t < BN) sCnt[t] = 0;
    __syncthreads();
    for(int j = gbase + t; j < gend; j += 512)
        atomicAdd(&sCnt[tmp[j].y - nb0], 1);
    __syncthreads();
    if(t < BN) sScan[t] = sCnt[t];
    __syncthreads();
    for(int off = 1; off < BN; off <<= 1){
        int v = 0;
        if(t < BN && t >= off) v = sScan[t - off];
        __syncthreads();
        if(t < BN) sScan[t] += v;
        __syncthreads();
    }
    if(t < BN) sCur[t] = sScan[t] - sCnt[t];
    if(t < BN && (nb0 + t) < NODES) rowst[nb0 + t] = gbase + (sScan[t] - sCnt[t]);
    if(b == 0 && t == 0) rowst[NODES] = EDGES;
    __syncthreads();
    for(int j = gbase + t; j < gend; j += 512){
        int2 e = tmp[j];
        int pos = atomicAdd(&sCur[e.y - nb0], 1);
        if(pos < BCAP) stage[pos] = e;
        else col[gbase + pos] = e.x;
    }
    __syncthreads();
    int lim = (cnt < BCAP) ? cnt : BCAP;
    for(int i = t; i < lim; i += 512)
        col[gbase + i] = stage[i].x;
}

// ---------------- MFMA GEMM: C[N x 64] = A[N x K] * W[K x 64] (+bias) (+scores)
// 64x64 tile, 4 waves, wave w owns rows 16w..16w+15; v_mfma_f32_16x16x32_bf16.
// Fragment layouts (HW-verified): A row=l&15, k=8*(l>>4)+e; B col=l&15, same k;
// D col=l&15, row=(l>>4)*4+reg.
// AMODE: 0 = A dtype follows flags[0]; 2 = A fp32 (workspace); 3 = A bf16 (h0).
// SCALEA=1 (with AMODE=2): h = elu(U * exp(m_n-M) * invZ) fused into staging.
template<int K, int AMODE, bool WITH_BIAS, bool WITH_SCORES, bool CBF16, int SCALEA>
__global__ __launch_bounds__(256) void k_gemm(
    const void* __restrict__ Aptr,
    const void* __restrict__ Wb,   int woff,
    const void* __restrict__ biasb,
    const void* __restrict__ attnb, int aoff,
    const int*  __restrict__ flags,
    void* __restrict__ Cout,
    float* __restrict__ s_src,
    float* __restrict__ s_dst,
    const float2* __restrict__ mzv,
    const float2* __restrict__ MZg)
{
    __shared__ short As[64][72];   // A tile bf16, rows x k-chunk
    __shared__ short Bs[64][72];   // W tile bf16 TRANSPOSED: [col][k-chunk]
    const bool wf32 = flags[0] != 0;
    const bool af32 = (AMODE == 2) ? true : ((AMODE == 3) ? false : wf32);
    const int t = threadIdx.x;
    const int block_row = blockIdx.x * 64;
    const int w  = t >> 6;           // wave id: rows 16w..16w+15
    const int l  = t & 63;
    const int srow = t >> 2;         // staging row 0..63
    const int sq   = t & 3;          // staging quarter (16 k's)
    const int grow_s = block_row + srow;

    float sA = 1.f;
    if constexpr (SCALEA == 1){
        float2 gz = MZg[0];
        float2 nm = (grow_s < NODES) ? mzv[grow_s] : make_float2(SENTINEL, 0.f);
        sA = __expf(nm.x - gz.x) * gz.y;
    }

    f32x4 acc[4] = { {0.f,0.f,0.f,0.f},{0.f,0.f,0.f,0.f},
                     {0.f,0.f,0.f,0.f},{0.f,0.f,0.f,0.f} };

    for(int kb = 0; kb < K; kb += 64){
        // ---- stage A chunk: As[row][k] = bf16(A[grow_s][kb+k]), k = sq*16..+15 ----
        {
            unsigned o[16];
            if(af32){
                const float4* av4 = (const float4*)((const float*)Aptr + (size_t)grow_s*K + kb);
                #pragma unroll
                for(int i=0;i<4;i++){
                    float4 u = make_float4(0.f,0.f,0.f,0.f);
                    if(grow_s < NODES) u = av4[sq*4 + i];
                    if constexpr (SCALEA == 1){
                        u.x = elu_fast(u.x*sA); u.y = elu_fast(u.y*sA);
                        u.z = elu_fast(u.z*sA); u.w = elu_fast(u.w*sA);
                    }
                    o[4*i+0]=f2b(u.x); o[4*i+1]=f2b(u.y);
                    o[4*i+2]=f2b(u.z); o[4*i+3]=f2b(u.w);
                }
            } else {
                const uint4* avb = (const uint4*)((const unsigned short*)Aptr + (size_t)grow_s*K + kb);
                #pragma unroll
                for(int i=0;i<2;i++){
                    uint4 u = make_uint4(0,0,0,0);
                    if(grow_s < NODES) u = avb[sq*2 + i];
                    o[8*i+0]=u.x&0xffffu; o[8*i+1]=u.x>>16;
                    o[8*i+2]=u.y&0xffffu; o[8*i+3]=u.y>>16;
                    o[8*i+4]=u.z&0xffffu; o[8*i+5]=u.z>>16;
                    o[8*i+6]=u.w&0xffffu; o[8*i+7]=u.w>>16;
                }
            }
            uint4* dst = (uint4*)&As[srow][sq*16];   // 144B row stride: 16B aligned
            dst[0] = make_uint4(o[0]|(o[1]<<16),  o[2]|(o[3]<<16),
                                o[4]|(o[5]<<16),  o[6]|(o[7]<<16));
            dst[1] = make_uint4(o[8]|(o[9]<<16),  o[10]|(o[11]<<16),
                                o[12]|(o[13]<<16),o[14]|(o[15]<<16));
        }
        // ---- stage W chunk transposed: Bs[col][k] (coalesced global reads) ----
        if(wf32){
            const float* wv = (const float*)Wb + woff + (size_t)kb*64;
            #pragma unroll
            for(int i=0;i<16;i++){
                int idx = t + 256*i;               // 0..4095 = k*64 + col
                Bs[idx & 63][idx >> 6] = (short)f2b(wv[idx]);
            }
        } else {
            const unsigned short* wv = (const unsigned short*)Wb + woff + (size_t)kb*64;
            #pragma unroll
            for(int i=0;i<16;i++){
                int idx = t + 256*i;
                Bs[idx & 63][idx >> 6] = (short)wv[idx];
            }
        }
        __syncthreads();
        // ---- MFMA: wave w rows, 4 col-subtiles, 2 K-steps of 32 ----
        #pragma unroll
        for(int s=0;s<2;s++){
            int k0 = s*32 + 8*(l >> 4);
            bf16x8 a = *(const bf16x8*)&As[16*w + (l & 15)][k0];
            #pragma unroll
            for(int c=0;c<4;c++){
                bf16x8 b = *(const bf16x8*)&Bs[16*c + (l & 15)][k0];
                acc[c] = __builtin_amdgcn_mfma_f32_16x16x32_bf16(a, b, acc[c], 0, 0, 0);
            }
        }
        __syncthreads();
    }

    // ---- epilogue: D col = l&15 (within subtile), row = (l>>4)*4 + r ----
    const int lg4 = (l >> 4) * 4;
    const int lc  = l & 15;
    float bias[4] = {0.f,0.f,0.f,0.f};
    if constexpr (WITH_BIAS){
        #pragma unroll
        for(int c=0;c<4;c++) bias[c] = ldin(biasb, 16*c + lc, wf32);
    }
    #pragma unroll
    for(int r=0;r<4;r++){
        int grow = block_row + 16*w + lg4 + r;
        if(grow < NODES){
            #pragma unroll
            for(int c=0;c<4;c++){
                float vv = acc[c][r] + bias[c];
                if constexpr (CBF16)
                    ((unsigned short*)Cout)[(size_t)grow*64 + 16*c + lc] = f2b(vv);
                else
                    ((float*)Cout)[(size_t)grow*64 + 16*c + lc] = vv;
            }
        }
    }
    if constexpr (WITH_SCORES){
        float as_[4], ad_[4];
        #pragma unroll
        for(int c=0;c<4;c++){
            as_[c] = ldin(attnb, aoff + 16*c + lc, wf32);
            ad_[c] = ldin(attnb, aoff + 64 + 16*c + lc, wf32);
        }
        #pragma unroll
        for(int r=0;r<4;r++){
            float ps = 0.f, pd = 0.f;
            #pragma unroll
            for(int c=0;c<4;c++){
                ps = fmaf(acc[c][r], as_[c], ps);
                pd = fmaf(acc[c][r], ad_[c], pd);
            }
            // reduce across the 16-lane col group (bits 0..3 of lane)
            ps += __shfl_xor(ps, 1, 64); pd += __shfl_xor(pd, 1, 64);
            ps += __shfl_xor(ps, 2, 64); pd += __shfl_xor(pd, 2, 64);
            ps += __shfl_xor(ps, 4, 64); pd += __shfl_xor(pd, 4, 64);
            ps += __shfl_xor(ps, 8, 64); pd += __shfl_xor(pd, 8, 64);
            int grow = block_row + 16*w + lg4 + r;
            if(lc == 0 && grow < NODES){ s_src[grow] = ps; s_dst[grow] = pd; }
        }
    }
}

// ---------------- S* = max over nodes of ssrc: grid-stride, 1 atomic per BLOCK ----
__global__ __launch_bounds__(256) void k_smax(const float* __restrict__ ssrc,
                                              unsigned* __restrict__ smaxk){
    int tid = blockIdx.x*256 + threadIdx.x;
    int stride = gridDim.x*256;
    float m = SENTINEL;
    for(int i = tid; i < NODES; i += stride) m = fmaxf(m, ssrc[i]);
    #pragma unroll
    for(int off=1; off<64; off<<=1) m = fmaxf(m, __shfl_xor(m, off, 64));
    __shared__ float sm[4];
    int w = threadIdx.x >> 6;
    if((threadIdx.x & 63) == 0) sm[w] = m;
    __syncthreads();
    if(threadIdx.x == 0){
        for(int i=1;i<4;i++) m = fmaxf(m, sm[i]);
        atomicMax(smaxk, fenc(m));
    }
}

// ---------------- fused aggregate: 8 NODES PER WAVE, 16-edge unrolled batches.
// Both 8-edge groups' col loads + ssrc gathers + all 16 wh16 gathers are issued
// in one scheduling region -> one latency exposure for the typical (deg<=16) node.
// Branchless: invalid/masked edges have w = 0 via exp underflow, gathers hit row 0.
// Shift m_n = S* + sdst[n]; emits unnormalized U_n and (m_n, z_n).
__global__ __launch_bounds__(256) void k_aggregate(const unsigned short* __restrict__ wh16,
    const int* __restrict__ row_start, const int* __restrict__ col,
    const float* __restrict__ ssrc, const float* __restrict__ sdst,
    const unsigned* __restrict__ smaxk,
    float* __restrict__ U, float2* __restrict__ mz)
{
    int gw = (blockIdx.x*256 + threadIdx.x) >> 3;   // one 8-lane slice per node
    if(gw >= NODES) return;
    int l8 = threadIdx.x & 7;
    int sb = (threadIdx.x & 63) & ~7;
    int c8 = l8 * 8;
    int beg = row_start[gw], end = row_start[gw+1];
    float sdn = sdst[gw];
    const float m = fdec(*smaxk) + sdn;
    float zl = 0.f;
    float acc[8] = {0.f,0.f,0.f,0.f,0.f,0.f,0.f,0.f};
    for(int base = beg; base < end; base += 16){
        int idx0 = base + l8;
        int idx1 = base + 8 + l8;
        bool v0 = idx0 < end, v1 = idx1 < end;
        int s0 = v0 ? col[idx0] : 0;
        int s1 = v1 ? col[idx1] : 0;
        float x0 = ssrc[s0] + sdn;
        float x1 = ssrc[s1] + sdn;
        float att0 = (v0 && x0 > 0.f) ? x0 : NEG_BIG_F;
        float att1 = (v1 && x1 > 0.f) ? x1 : NEG_BIG_F;
        float w0 = __expf(att0 - m);
        float w1 = __expf(att1 - m);
        zl += w0 + w1;
        #pragma unroll
        for(int j = 0; j < 8; j++){
            int   s = __shfl(s0, sb + j, 64);        // depends only on col load
            float a = __shfl(w0, sb + j, 64);
            uint4 u = *(const uint4*)&wh16[(size_t)s*64 + c8];
            acc[0] = fmaf(a, bits2f(u.x & 0xffffu), acc[0]);
            acc[1] = fmaf(a, bits2f(u.x >> 16),     acc[1]);
            acc[2] = fmaf(a, bits2f(u.y & 0xffffu), acc[2]);
            acc[3] = fmaf(a, bits2f(u.y >> 16),     acc[3]);
            acc[4] = fmaf(a, bits2f(u.z & 0xffffu), acc[4]);
            acc[5] = fmaf(a, bits2f(u.z >> 16),     acc[5]);
            acc[6] = fmaf(a, bits2f(u.w & 0xffffu), acc[6]);
            acc[7] = fmaf(a, bits2f(u.w >> 16),     acc[7]);
        }
        #pragma unroll
        for(int j = 0; j < 8; j++){
            int   s = __shfl(s1, sb + j, 64);
            float a = __shfl(w1, sb + j, 64);
            uint4 u = *(const uint4*)&wh16[(size_t)s*64 + c8];
            acc[0] = fmaf(a, bits2f(u.x & 0xffffu), acc[0]);
            acc[1] = fmaf(a, bits2f(u.x >> 16),     acc[1]);
            acc[2] = fmaf(a, bits2f(u.y & 0xffffu), acc[2]);
            acc[3] = fmaf(a, bits2f(u.y >> 16),     acc[3]);
            acc[4] = fmaf(a, bits2f(u.z & 0xffffu), acc[4]);
            acc[5] = fmaf(a, bits2f(u.z >> 16),     acc[5]);
            acc[6] = fmaf(a, bits2f(u.w & 0xffffu), acc[6]);
            acc[7] = fmaf(a, bits2f(u.w >> 16),     acc[7]);
        }
    }
    zl += __shfl_xor(zl, 1, 64);
    zl += __shfl_xor(zl, 2, 64);
    zl += __shfl_xor(zl, 4, 64);
    if(l8 == 0) mz[gw] = make_float2(m, zl);
    *(float4*)&U[(size_t)gw*64 + c8 + 0] = make_float4(acc[0],acc[1],acc[2],acc[3]);
    *(float4*)&U[(size_t)gw*64 + c8 + 4] = make_float4(acc[4],acc[5],acc[6],acc[7]);
}

// ---------------- node (m,z) -> global (M, 1/Z), two-stage ----------------
__global__ __launch_bounds__(256) void k_mz_part(const float2* __restrict__ mz,
                                                 float2* __restrict__ bmz){
    int tid = blockIdx.x*256 + threadIdx.x;
    int stride = gridDim.x*256;
    float m = SENTINEL, z = 0.f;
    for(int i = tid; i < NODES; i += stride){
        float2 e = mz[i];
        float M = fmaxf(m, e.x);
        z = z*__expf(m - M) + e.y*__expf(e.x - M);
        m = M;
    }
    for(int off=1; off<64; off<<=1){
        float m2 = __shfl_xor(m, off, 64), z2 = __shfl_xor(z, off, 64);
        float M = fmaxf(m, m2);
        z = z*__expf(m - M) + z2*__expf(m2 - M);
        m = M;
    }
    __shared__ float sm[4], sz[4];
    int w = threadIdx.x >> 6;
    if((threadIdx.x & 63) == 0){ sm[w] = m; sz[w] = z; }
    __syncthreads();
    if(threadIdx.x == 0){
        for(int i=1;i<4;i++){
            float M = fmaxf(m, sm[i]);
            z = z*__expf(m - M) + sz[i]*__expf(sm[i] - M);
            m = M;
        }
        bmz[blockIdx.x] = make_float2(m, z);
    }
}

__global__ __launch_bounds__(256) void k_mz_final(const float2* __restrict__ bmz,
                                                  float2* __restrict__ MZ,
                                                  unsigned* __restrict__ smaxk){
    int t = threadIdx.x;
    float m = SENTINEL, z = 0.f;
    for(int i = t; i < MZPB; i += 256){
        float2 e = bmz[i];
        float M = fmaxf(m, e.x);
        z = z*__expf(m - M) + e.y*__expf(e.x - M);
        m = M;
    }
    for(int off=1; off<64; off<<=1){
        float m2 = __shfl_xor(m, off, 64), z2 = __shfl_xor(z, off, 64);
        float M = fmaxf(m, m2);
        z = z*__expf(m - M) + z2*__expf(m2 - M);
        m = M;
    }
    __shared__ float sm[4], sz[4];
    int w = t >> 6;
    if((t & 63) == 0){ sm[w] = m; sz[w] = z; }
    __syncthreads();
    if(t == 0){
        for(int i=1;i<4;i++){
            float M = fmaxf(m, sm[i]);
            z = z*__expf(m - M) + sz[i]*__expf(sm[i] - M);
            m = M;
        }
        MZ[0] = make_float2(m, 1.0f / z);
        smaxk[0] = 0u;   // reset S* accumulator for the next layer
    }
}

// ---------------- fused out-proj + elu + log_softmax, GEMM-tiled (fp32 output).
// Input is unnormalized U2: apply h = elu(U * exp(m_n - M) * invZ) during H-load.
__global__ __launch_bounds__(256) void k_out(const float* __restrict__ h,
    const float2* __restrict__ mzv, const float2* __restrict__ MZg,
    const void* __restrict__ Wo, const void* __restrict__ bo,
    const int* __restrict__ flags, float* __restrict__ out)
{
    __shared__ float Ht[64][65];
    __shared__ float Wsh[64][44];
    __shared__ float logits[64][44];
    __shared__ float rlz[64];
    bool f32 = flags[0] != 0;
    int t = threadIdx.x;
    int block_row = blockIdx.x * 64;

    for(int i = t; i < 64*NCLS; i += 256){
        Wsh[i/NCLS][i%NCLS] = ldin(Wo, i, f32);
    }
    {
        int r_load = t >> 2, q = t & 3;
        int grow = block_row + r_load;
        const float4* hv = (const float4*)h;
        float2 gz = MZg[0];
        float2 nm = (grow < NODES) ? mzv[grow] : make_float2(SENTINEL, 0.f);
        float sA = __expf(nm.x - gz.x) * gz.y;
        #pragma unroll
        for(int i = 0; i < 4; i++){
            int vi = q + 4*i;
            float4 u = make_float4(0.f,0.f,0.f,0.f);
            if(grow < NODES) u = hv[(size_t)grow*16 + vi];
            u.x = elu_fast(u.x*sA); u.y = elu_fast(u.y*sA);
            u.z = elu_fast(u.z*sA); u.w = elu_fast(u.w*sA);
            Ht[vi*4+0][r_load] = u.x; Ht[vi*4+1][r_load] = u.y;
            Ht[vi*4+2][r_load] = u.z; Ht[vi*4+3][r_load] = u.w;
        }
    }
    __syncthreads();

    int cg = t & 15, rg = t >> 4;
    int c0 = cg * 4, r0 = rg * 4;
    if(cg < 10){
        float acc[4][4] = {{0.f,0.f,0.f,0.f},{0.f,0.f,0.f,0.f},{0.f,0.f,0.f,0.f},{0.f,0.f,0.f,0.f}};
        #pragma unroll 8
        for(int k = 0; k < 64; k++){
            float4 a = *(const float4*)&Ht[k][r0];
            float4 w = *(const float4*)&Wsh[k][c0];
            float av4[4] = {a.x,a.y,a.z,a.w};
            float wv4[4] = {w.x,w.y,w.z,w.w};
            #pragma unroll
            for(int i=0;i<4;i++)
                #pragma unroll
                for(int j=0;j<4;j++)
                    acc[i][j] = fmaf(av4[i], wv4[j], acc[i][j]);
        }
        float b[4];
        #pragma unroll
        for(int j=0;j<4;j++) b[j] = ldin(bo, c0+j, f32);
        #pragma unroll
        for(int i=0;i<4;i++)
            #pragma unroll
            for(int j=0;j<4;j++){
                logits[r0+i][c0+j] = elu_fast(acc[i][j] + b[j]);
            }
    }
    __syncthreads();

    {
        int r = t >> 2, qq = t & 3;
        float m = SENTINEL;
        #pragma unroll
        for(int i=0;i<10;i++) m = fmaxf(m, logits[r][qq*10 + i]);
        m = fmaxf(m, __shfl_xor(m, 1, 64));
        m = fmaxf(m, __shfl_xor(m, 2, 64));
        float s = 0.f;
        #pragma unroll
        for(int i=0;i<10;i++) s += __expf(logits[r][qq*10 + i] - m);
        s += __shfl_xor(s, 1, 64);
        s += __shfl_xor(s, 2, 64);
        if(qq == 0) rlz[r] = m + logf(s);
    }
    __syncthreads();

    for(int i = t; i < 64*NCLS; i += 256){
        int rr = i / NCLS, cc = i % NCLS;
        if(block_row + rr < NODES)
            out[(size_t)(block_row)*NCLS + i] = logits[rr][cc] - rlz[rr];
    }
}

extern "C" void kernel_launch(void* const* d_in, const int* in_sizes, int n_in,
                              void* d_out, int out_size, void* d_ws, size_t ws_size,
                              hipStream_t stream)
{
    const void* x      = d_in[0];
    const int*  ei     = (const int*)d_in[1];
    const void* emb_w  = d_in[2];
    const void* emb_b  = d_in[3];
    const void* Ws     = d_in[4];
    const void* attn_a = d_in[5];
    const void* out_w  = d_in[6];
    const void* out_b  = d_in[7];
    float* out = (float*)d_out;

    char* ws = (char*)d_ws;
    size_t off = 0;
    auto alloc = [&](size_t bytes)->char*{
        char* p = ws + off;
        off = (off + bytes + 255) & ~(size_t)255;
        return p;
    };
    int*    flags   = (int*)   alloc(256);
    float*  h       = (float*) alloc((size_t)NODES*HID*4);   // U1 / U2; aliased as phase-A tmp
    unsigned short* h0 = (unsigned short*)alloc((size_t)NODES*HID*2);  // emb out (bf16)
    unsigned short* wh16 = (unsigned short*)alloc((size_t)NODES*HID*2);
    float*  ssrc    = (float*) alloc((size_t)NODES*4);
    float*  sdst    = (float*) alloc((size_t)NODES*4);
    int*    rowst   = (int*)   alloc((size_t)(NODES+1)*4);
    int*    col     = (int*)   alloc((size_t)EDGES*4);
    float2* mz      = (float2*)alloc((size_t)NODES*8);
    int*    bdeg    = (int*)   alloc(NBUCK*4);
    int*    bstart  = (int*)   alloc((NBUCK+1)*4);
    int*    bcursor = (int*)   alloc(NBUCK*4);
    float2* bmz     = (float2*)alloc(MZPB*8);
    float2* MZ      = (float2*)alloc(16);
    unsigned* smaxk = (unsigned*)alloc(256);

    int2* tmp = (int2*)h;   // consumed by k_bucket_sort before aggregates write h

    k_detect<<<1, 256, 0, stream>>>((const unsigned*)x, (const unsigned*)ei, flags);

    hipMemsetAsync(bdeg, 0, NBUCK*4, stream);
    hipMemsetAsync(smaxk, 0, 4, stream);   // encoded -inf
    k_bhist<<<256, 256, 0, stream>>>(ei, flags, bdeg);
    k_bscan<<<1, 256, 0, stream>>>(bdeg, bstart, bcursor);
    k_bucket_scatter<<<NCHUNK, 256, 0, stream>>>(ei, flags, bcursor, tmp);
    k_bucket_sort<<<NBUCK, 512, 0, stream>>>(tmp, bstart, col, rowst);

    // emb: x[N x 128] @ emb_w -> h0 (bf16; consumed only as layer-0 A operand)
    k_gemm<INDIM, 0, true, false, true, 0><<<(NODES+63)/64, 256, 0, stream>>>(
        x, emb_w, 0, emb_b, nullptr, 0, flags, h0, nullptr, nullptr, nullptr, nullptr);

    // ---- layer 0: A = h0 (bf16) ----
    k_gemm<HID, 3, false, true, true, 0><<<(NODES+63)/64, 256, 0, stream>>>(
        h0, Ws, 0, nullptr, attn_a, 0, flags, wh16, ssrc, sdst, nullptr, nullptr);
    k_smax<<<SMB, 256, 0, stream>>>(ssrc, smaxk);
    k_aggregate<<<(NODES*8 + 255)/256, 256, 0, stream>>>(wh16, rowst, col, ssrc, sdst, smaxk, h, mz);
    k_mz_part <<<MZPB, 256, 0, stream>>>(mz, bmz);
    k_mz_final<<<1, 256, 0, stream>>>(bmz, MZ, smaxk);   // also resets smaxk

    // ---- layer 1: A = U1 (fp32) with deferred normalization + ELU fused ----
    k_gemm<HID, 2, false, true, true, 1><<<(NODES+63)/64, 256, 0, stream>>>(
        h, Ws, HID*HID, nullptr, attn_a, 2*HID, flags, wh16, ssrc, sdst, mz, MZ);
    k_smax<<<SMB, 256, 0, stream>>>(ssrc, smaxk);
    k_aggregate<<<(NODES*8 + 255)/256, 256, 0, stream>>>(wh16, rowst, col, ssrc, sdst, smaxk, h, mz);
    k_mz_part <<<MZPB, 256, 0, stream>>>(mz, bmz);
    k_mz_final<<<1, 256, 0, stream>>>(bmz, MZ, smaxk);

    k_out<<<(NODES+63)/64, 256, 0, stream>>>(h, mz, MZ, out_w, out_b, flags, out);
}